// Round 1
// baseline (511.602 us; speedup 1.0000x reference)
//
#include <hip/hip_runtime.h>
#include <math.h>

#define B_ 2
#define T_ 128
#define Cc 384
#define NH_ 6
#define HD 64
#define Hh 768
#define P_ 4
#define M_ 16
#define PL_ 20
#define TT 148   /* PL_ + T_ */

static inline int cdiv(int a, int b) { return (a + b - 1) / b; }

// ---------------- workspace layout (floats) ----------------
enum : long {
  OFF_XN   = 0,
  OFF_SEQ  = OFF_XN   + (long)B_*T_*Cc,
  OFF_HID  = OFF_SEQ  + (long)B_*TT*Cc,
  OFF_RETR = OFF_HID  + (long)M_*Hh,
  OFF_QKV  = OFF_RETR + (long)M_*Cc,
  OFF_Y    = OFF_QKV  + (long)B_*TT*3*Cc,
  OFF_H1   = OFF_Y    + (long)B_*T_*Cc,
  OFF_H2N  = OFF_H1   + (long)B_*T_*Cc,
  OFF_FC   = OFF_H2N  + (long)B_*T_*Cc,
  OFF_H2   = OFF_FC   + (long)B_*T_*4*Cc,
  OFF_KM   = OFF_H2   + (long)B_*T_*Cc,
  OFF_VM   = OFF_KM   + (long)B_*T_*Cc,
  OFF_HH   = OFF_VM   + (long)B_*T_*Cc,
  OFF_A    = OFF_HH   + (long)B_*T_*Hh,
  OFF_ERR  = OFF_A    + (long)B_*T_*Hh,
  OFF_DH   = OFF_ERR  + (long)B_*T_*Cc,
  OFF_W1F  = OFF_DH   + (long)B_*T_*Hh,
  OFF_W2F  = OFF_W1F  + (long)B_*Cc*Hh,
  OFF_U    = OFF_W2F  + (long)B_*Hh*Cc,
  OFF_COEF = OFF_U    + (long)B_*T_*Hh
};

// ---------------- activation helpers ----------------
template<int ACT>
__device__ __forceinline__ float act_apply(float v) {
  if (ACT == 1) { // gelu (tanh approx, jax.nn.gelu default)
    float x3 = v*v*v;
    return 0.5f*v*(1.f + tanhf(0.7978845608028654f*(v + 0.044715f*x3)));
  } else if (ACT == 2) { // silu
    return v / (1.f + expf(-v));
  }
  return v;
}

// ---------------- LayerNorm: one block per row, C=384, 384 threads ----------------
__global__ __launch_bounds__(384)
void ln_k(const float* __restrict__ x, const float* __restrict__ g,
          const float* __restrict__ bvec, float* __restrict__ out)
{
  const int C = Cc;
  int row = blockIdx.x;
  int tid = threadIdx.x;
  float v = x[(long)row*C + tid];
  int lane = tid & 63, wid = tid >> 6;
  __shared__ float red[6];
  __shared__ float mu_s, rstd_s;
  float s = v;
  #pragma unroll
  for (int off = 32; off; off >>= 1) s += __shfl_down(s, off);
  if (lane == 0) red[wid] = s;
  __syncthreads();
  if (tid == 0) { float t = 0; for (int i = 0; i < 6; ++i) t += red[i]; mu_s = t / (float)C; }
  __syncthreads();
  float d = v - mu_s;
  float sq = d*d;
  #pragma unroll
  for (int off = 32; off; off >>= 1) sq += __shfl_down(sq, off);
  if (lane == 0) red[wid] = sq;
  __syncthreads();
  if (tid == 0) { float t = 0; for (int i = 0; i < 6; ++i) t += red[i]; rstd_s = rsqrtf(t / (float)C + 1e-5f); }
  __syncthreads();
  out[(long)row*C + tid] = d * rstd_s * g[tid] + bvec[tid];
}

// ---------------- generic 32x32-tile GEMM, batched via z ----------------
// C[m,n] = epi( sum_k A[m,k]*B[k,n] )  ; epi = (+bias) -> act -> (+res_scale*res)
template<int ACT, bool HAS_BIAS, bool HAS_RES>
__global__ __launch_bounds__(256)
void gemm32(const float* __restrict__ A, const float* __restrict__ Bm,
            const float* __restrict__ bias, const float* __restrict__ res,
            float res_scale, float* __restrict__ C,
            int M, int N, int K, long sA, long sB, long sC, long sR)
{
  int z = blockIdx.z;
  A += (long)z * sA; Bm += (long)z * sB; C += (long)z * sC;
  if (HAS_RES) res += (long)z * sR;
  __shared__ float As[32][33];
  __shared__ float Bs[32][33];
  int tx = threadIdx.x, ty = threadIdx.y;
  int r0 = blockIdx.y*32 + ty, r1 = r0 + 16;
  int c0 = blockIdx.x*32 + tx, c1 = c0 + 16;
  float a00 = 0.f, a01 = 0.f, a10 = 0.f, a11 = 0.f;
  for (int kt = 0; kt < K; kt += 32) {   // K is always a multiple of 32 here
    As[ty][tx]       = (r0 < M) ? A[(long)r0*K + kt+tx]    : 0.f;
    As[ty][tx+16]    = (r0 < M) ? A[(long)r0*K + kt+tx+16] : 0.f;
    As[ty+16][tx]    = (r1 < M) ? A[(long)r1*K + kt+tx]    : 0.f;
    As[ty+16][tx+16] = (r1 < M) ? A[(long)r1*K + kt+tx+16] : 0.f;
    Bs[ty][tx]       = (c0 < N) ? Bm[(long)(kt+ty)*N + c0]    : 0.f;
    Bs[ty][tx+16]    = (c1 < N) ? Bm[(long)(kt+ty)*N + c1]    : 0.f;
    Bs[ty+16][tx]    = (c0 < N) ? Bm[(long)(kt+ty+16)*N + c0] : 0.f;
    Bs[ty+16][tx+16] = (c1 < N) ? Bm[(long)(kt+ty+16)*N + c1] : 0.f;
    __syncthreads();
    #pragma unroll
    for (int kk = 0; kk < 32; ++kk) {
      float av0 = As[ty][kk], av1 = As[ty+16][kk];
      float bv0 = Bs[kk][tx], bv1 = Bs[kk][tx+16];
      a00 += av0*bv0; a01 += av0*bv1; a10 += av1*bv0; a11 += av1*bv1;
    }
    __syncthreads();
  }
  auto store = [&](int r, int c, float acc) {
    float v = acc;
    if (HAS_BIAS) v += bias[c];
    v = act_apply<ACT>(v);
    if (HAS_RES) v += res_scale * res[(long)r*N + c];
    C[(long)r*N + c] = v;
  };
  if (r0 < M) { if (c0 < N) store(r0, c0, a00); if (c1 < N) store(r0, c1, a01); }
  if (r1 < M) { if (c0 < N) store(r1, c0, a10); if (c1 < N) store(r1, c1, a11); }
}

// ---------------- dh = (err @ mem_w2^T) * silu'(hh) ----------------
// DH[m,n] = (sum_k E[m,k]*W2[n,k]) * dsilu(HH[m,n]);  W2 is [N,K] row-major
__global__ __launch_bounds__(256)
void gemm_bt_dsilu(const float* __restrict__ E, const float* __restrict__ W2,
                   const float* __restrict__ HH, float* __restrict__ DH,
                   int M, int N, int K)
{
  __shared__ float As[16][17], Bs[16][17];
  int tx = threadIdx.x, ty = threadIdx.y;
  int row = blockIdx.y*16 + ty, col = blockIdx.x*16 + tx;
  float acc = 0.f;
  for (int kt = 0; kt < K; kt += 16) {
    As[ty][tx] = (row < M) ? E[(long)row*K + kt+tx] : 0.f;
    int nrow = blockIdx.x*16 + ty;
    Bs[tx][ty] = (nrow < N) ? W2[(long)nrow*K + kt+tx] : 0.f;   // Bs[k_local][n_local]
    __syncthreads();
    #pragma unroll
    for (int kk = 0; kk < 16; ++kk) acc += As[ty][kk]*Bs[kk][tx];
    __syncthreads();
  }
  if (row < M && col < N) {
    float h = HH[(long)row*N + col];
    float sg = 1.f/(1.f + expf(-h));
    DH[(long)row*N + col] = acc * (sg*(1.f + h*(1.f - sg)));
  }
}

// ---------------- weight update: Cout = dpow*W0 + scale * sum_k coef[k]*A[k,m]*Bm[k,n] ----------------
// A is [K,M] row-major (per batch), Bm is [K,N] row-major (per batch), W0 shared.
__global__ __launch_bounds__(256)
void gemm_at_coef(const float* __restrict__ A, const float* __restrict__ Bm,
                  const float* __restrict__ coef, const float* __restrict__ W0,
                  float* __restrict__ Cout, int M, int N, int K,
                  long sA, long sB, long sC, float scale, float dpow)
{
  int z = blockIdx.z;
  A += (long)z * sA; Bm += (long)z * sB; Cout += (long)z * sC;
  __shared__ float As[16][17], Bs[16][17];
  int tx = threadIdx.x, ty = threadIdx.y;
  int mbase = blockIdx.y*16;
  int row = mbase + ty, col = blockIdx.x*16 + tx;
  float acc = 0.f;
  for (int kt = 0; kt < K; kt += 16) {
    As[ty][tx] = (mbase+tx < M) ? A[(long)(kt+ty)*M + mbase+tx] * coef[kt+ty] : 0.f;
    Bs[ty][tx] = (col < N) ? Bm[(long)(kt+ty)*N + col] : 0.f;
    __syncthreads();
    #pragma unroll
    for (int kk = 0; kk < 16; ++kk) acc += As[kk][ty]*Bs[kk][tx];
    __syncthreads();
  }
  if (row < M && col < N)
    Cout[(long)row*N + col] = dpow*W0[(long)row*N + col] + scale*acc;
}

// ---------------- attention: one wave per (b, h, suffix q-row) ----------------
// For q-row >= PL the prefix-LM mask reduces to causal: allowed <=> k <= qr.
__global__ __launch_bounds__(64)
void attn_k(const float* __restrict__ qkv, float* __restrict__ yb)
{
  const int Cq = 3*Cc;
  int lane = threadIdx.x;
  int qr = PL_ + blockIdx.x;
  int h  = blockIdx.y;
  int b  = blockIdx.z;
  const float* base = qkv + (long)(b*TT)*Cq;
  __shared__ float qs[HD];
  __shared__ float p[TT];
  qs[lane] = base[(long)qr*Cq + h*HD + lane];
  __syncthreads();
  float mloc = -1e30f;
  for (int k = lane; k < TT; k += 64) {
    float s = -1e30f;
    if (k <= qr) {
      const float* kp = base + (long)k*Cq + Cc + h*HD;
      float acc = 0.f;
      #pragma unroll
      for (int d2 = 0; d2 < HD; ++d2) acc += qs[d2]*kp[d2];
      s = acc * 0.125f;   // 1/sqrt(64)
    }
    p[k] = s;
    mloc = fmaxf(mloc, s);
  }
  #pragma unroll
  for (int off = 32; off; off >>= 1) mloc = fmaxf(mloc, __shfl_xor(mloc, off));
  float ssum = 0.f;
  for (int k = lane; k < TT; k += 64) {
    float e = (k <= qr) ? expf(p[k] - mloc) : 0.f;
    p[k] = e;
    ssum += e;
  }
  #pragma unroll
  for (int off = 32; off; off >>= 1) ssum += __shfl_xor(ssum, off);
  __syncthreads();
  float inv = 1.f / ssum;
  float acc = 0.f;
  for (int k = 0; k <= qr; ++k)
    acc += p[k] * base[(long)k*Cq + 2*Cc + h*HD + lane];
  yb[((long)(b*T_ + blockIdx.x))*Cc + h*HD + lane] = acc * inv;
}

// ---------------- small helpers ----------------
__global__ void assemble_seq_k(const float* __restrict__ persist, const float* __restrict__ retr,
                               const float* __restrict__ xn, float* __restrict__ seq)
{
  int i = blockIdx.x*blockDim.x + threadIdx.x;
  const int total = B_*TT*Cc;
  if (i >= total) return;
  int c = i % Cc;
  int r = (i / Cc) % TT;
  int b = i / (Cc*TT);
  float v;
  if (r < P_)        v = persist[r*Cc + c];
  else if (r < PL_)  v = retr[(r - P_)*Cc + c];
  else               v = xn[((long)b*T_ + (r - PL_))*Cc + c];
  seq[i] = v;
}

__global__ void silu_k(const float* __restrict__ in, float* __restrict__ out, int n)
{
  int i = blockIdx.x*blockDim.x + threadIdx.x;
  if (i < n) { float v = in[i]; out[i] = v / (1.f + expf(-v)); }
}

__global__ void init_coef_k(float* __restrict__ coef)
{
  int k = threadIdx.x;  // 0..127
  if (k < T_) {
    int e = T_ - k;  // n+1 = 128-k
    coef[k] = (powf(0.999f, (float)e) - powf(0.9f, (float)e)) / 0.099f;
  }
}

// ---------------- launch ----------------
extern "C" void kernel_launch(void* const* d_in, const int* in_sizes, int n_in,
                              void* d_out, int out_size, void* d_ws, size_t ws_size,
                              hipStream_t stream)
{
  const float* x         = (const float*)d_in[0];
  const float* c_attn_w  = (const float*)d_in[1];
  const float* c_attn_b  = (const float*)d_in[2];
  const float* c_proj_w  = (const float*)d_in[3];
  const float* c_proj_b  = (const float*)d_in[4];
  const float* ln1_g     = (const float*)d_in[5];
  const float* ln1_b     = (const float*)d_in[6];
  const float* ln2_g     = (const float*)d_in[7];
  const float* ln2_b     = (const float*)d_in[8];
  const float* fc_w      = (const float*)d_in[9];
  const float* fc_b      = (const float*)d_in[10];
  const float* pr_w      = (const float*)d_in[11];
  const float* pr_b      = (const float*)d_in[12];
  const float* mem_w1    = (const float*)d_in[13];
  const float* mem_w2    = (const float*)d_in[14];
  const float* wk        = (const float*)d_in[15];
  const float* wv        = (const float*)d_in[16];
  const float* mem_q     = (const float*)d_in[17];
  const float* persist   = (const float*)d_in[18];

  float* ws   = (float*)d_ws;
  float* xn   = ws + OFF_XN;
  float* seq  = ws + OFF_SEQ;
  float* hid  = ws + OFF_HID;
  float* retr = ws + OFF_RETR;
  float* qkv  = ws + OFF_QKV;
  float* yb   = ws + OFF_Y;
  float* h1   = ws + OFF_H1;
  float* h2n  = ws + OFF_H2N;
  float* fco  = ws + OFF_FC;
  float* h2   = ws + OFF_H2;
  float* km   = ws + OFF_KM;
  float* vm   = ws + OFF_VM;
  float* hh   = ws + OFF_HH;
  float* ab   = ws + OFF_A;
  float* errb = ws + OFF_ERR;
  float* dhb  = ws + OFF_DH;
  float* w1f  = ws + OFF_W1F;
  float* w2f  = ws + OFF_W2F;
  float* ub   = ws + OFF_U;
  float* coef = ws + OFF_COEF;
  float* outp = (float*)d_out;

  dim3 tb16(16, 16);
  const float dpow  = powf(0.999f, 128.f);   // decay^T
  const float scale = -0.001f;               // -(LR*(1-MOM))

  // coefficients for the collapsed momentum+decay scan
  init_coef_k<<<1, 128, 0, stream>>>(coef);

  // xn = LN1(x)
  ln_k<<<B_*T_, Cc, 0, stream>>>(x, ln1_g, ln1_b, xn);

  // retr = silu(mem_q @ mem_w1) @ mem_w2
  gemm32<2,false,false><<<dim3(cdiv(Hh,32), 1, 1), tb16, 0, stream>>>(
      mem_q, mem_w1, nullptr, nullptr, 0.f, hid, M_, Hh, Cc, 0,0,0,0);
  gemm32<0,false,false><<<dim3(cdiv(Cc,32), 1, 1), tb16, 0, stream>>>(
      hid, mem_w2, nullptr, nullptr, 0.f, retr, M_, Cc, Hh, 0,0,0,0);

  // seq = [persist; retr; xn] per batch
  assemble_seq_k<<<cdiv(B_*TT*Cc, 256), 256, 0, stream>>>(persist, retr, xn, seq);

  // qkv = seq @ c_attn_w + b   (M = B*148 flattened)
  gemm32<0,true,false><<<dim3(cdiv(3*Cc,32), cdiv(B_*TT,32), 1), tb16, 0, stream>>>(
      seq, c_attn_w, c_attn_b, nullptr, 0.f, qkv, B_*TT, 3*Cc, Cc, 0,0,0,0);

  // attention (suffix rows only)
  attn_k<<<dim3(T_, NH_, B_), 64, 0, stream>>>(qkv, yb);

  // h1 = x + yb @ c_proj_w + c_proj_b
  gemm32<0,true,true><<<dim3(cdiv(Cc,32), cdiv(B_*T_,32), 1), tb16, 0, stream>>>(
      yb, c_proj_w, c_proj_b, x, 1.f, h1, B_*T_, Cc, Cc, 0,0,0,0);

  // h2n = LN2(h1)
  ln_k<<<B_*T_, Cc, 0, stream>>>(h1, ln2_g, ln2_b, h2n);

  // fco = gelu(h2n @ fc_w + fc_b)
  gemm32<1,true,false><<<dim3(cdiv(4*Cc,32), cdiv(B_*T_,32), 1), tb16, 0, stream>>>(
      h2n, fc_w, fc_b, nullptr, 0.f, fco, B_*T_, 4*Cc, Cc, 0,0,0,0);

  // h2 = h1 + fco @ pr_w + pr_b
  gemm32<0,true,true><<<dim3(cdiv(Cc,32), cdiv(B_*T_,32), 1), tb16, 0, stream>>>(
      fco, pr_w, pr_b, h1, 1.f, h2, B_*T_, Cc, 4*Cc, 0,0,0,0);

  // km = xn @ wk ; vm = xn @ wv
  gemm32<0,false,false><<<dim3(cdiv(Cc,32), cdiv(B_*T_,32), 1), tb16, 0, stream>>>(
      xn, wk, nullptr, nullptr, 0.f, km, B_*T_, Cc, Cc, 0,0,0,0);
  gemm32<0,false,false><<<dim3(cdiv(Cc,32), cdiv(B_*T_,32), 1), tb16, 0, stream>>>(
      xn, wv, nullptr, nullptr, 0.f, vm, B_*T_, Cc, Cc, 0,0,0,0);

  // hh = km @ mem_w1 ; a = silu(hh)
  gemm32<0,false,false><<<dim3(cdiv(Hh,32), cdiv(B_*T_,32), 1), tb16, 0, stream>>>(
      km, mem_w1, nullptr, nullptr, 0.f, hh, B_*T_, Hh, Cc, 0,0,0,0);
  silu_k<<<cdiv(B_*T_*Hh, 256), 256, 0, stream>>>(hh, ab, B_*T_*Hh);

  // err = a @ mem_w2 - vm
  gemm32<0,false,true><<<dim3(cdiv(Cc,32), cdiv(B_*T_,32), 1), tb16, 0, stream>>>(
      ab, mem_w2, nullptr, vm, -1.f, errb, B_*T_, Cc, Hh, 0,0,0,0);

  // dh = (err @ mem_w2^T) * silu'(hh)
  gemm_bt_dsilu<<<dim3(cdiv(Hh,16), cdiv(B_*T_,16), 1), tb16, 0, stream>>>(
      errb, mem_w2, hh, dhb, B_*T_, Hh, Cc);

  // w1f[b] = dpow*mem_w1 + scale * sum_t coef[t]*km[b,t,:]⊗dh[b,t,:]
  gemm_at_coef<<<dim3(cdiv(Hh,16), cdiv(Cc,16), B_), tb16, 0, stream>>>(
      km, dhb, coef, mem_w1, w1f, Cc, Hh, T_,
      (long)T_*Cc, (long)T_*Hh, (long)Cc*Hh, scale, dpow);

  // w2f[b] = dpow*mem_w2 + scale * sum_t coef[t]*a[b,t,:]⊗err[b,t,:]
  gemm_at_coef<<<dim3(cdiv(Cc,16), cdiv(Hh,16), B_), tb16, 0, stream>>>(
      ab, errb, coef, mem_w2, w2f, Hh, Cc, T_,
      (long)T_*Hh, (long)T_*Cc, (long)Hh*Cc, scale, dpow);

  // u = silu(h2 @ w1f)   (batched, per-batch B operand)
  gemm32<2,false,false><<<dim3(cdiv(Hh,32), cdiv(T_,32), B_), tb16, 0, stream>>>(
      h2, w1f, nullptr, nullptr, 0.f, ub, T_, Hh, Cc,
      (long)T_*Cc, (long)Cc*Hh, (long)T_*Hh, 0);

  // out = h2 + u @ w2f
  gemm32<0,false,true><<<dim3(cdiv(Cc,32), cdiv(T_,32), B_), tb16, 0, stream>>>(
      ub, w2f, nullptr, h2, 1.f, outp, T_, Cc, Hh,
      (long)T_*Hh, (long)Hh*Cc, (long)T_*Cc, (long)T_*Cc);
}

// Round 2
// 281.220 us; speedup vs baseline: 1.8192x; 1.8192x over previous
//
#include <hip/hip_runtime.h>
#include <math.h>

#define B_ 2
#define T_ 128
#define Cc 384
#define NH_ 6
#define HD 64
#define Hh 768
#define P_ 4
#define M_ 16
#define PL_ 20
#define TT 148   /* PL_ + T_ */
#define BK 32

typedef float4 f4;
static inline int cdiv(int a, int b) { return (a + b - 1) / b; }

// ---------------- workspace layout (floats) ----------------
enum : long {
  OFF_SEQ  = 0,
  OFF_HID  = OFF_SEQ  + (long)B_*TT*Cc,
  OFF_QKV  = OFF_HID  + (long)M_*Hh,
  OFF_Y    = OFF_QKV  + (long)B_*TT*3*Cc,
  OFF_H1   = OFF_Y    + (long)B_*T_*Cc,
  OFF_H2N  = OFF_H1   + (long)B_*T_*Cc,
  OFF_FC   = OFF_H2N  + (long)B_*T_*Cc,
  OFF_H2   = OFF_FC   + (long)B_*T_*4*Cc,
  OFF_KM   = OFF_H2   + (long)B_*T_*Cc,
  OFF_VM   = OFF_KM   + (long)B_*T_*Cc,
  OFF_HH   = OFF_VM   + (long)B_*T_*Cc,
  OFF_A    = OFF_HH   + (long)B_*T_*Hh,
  OFF_ERR  = OFF_A    + (long)B_*T_*Hh,
  OFF_DH   = OFF_ERR  + (long)B_*T_*Cc,
  OFF_W1F  = OFF_DH   + (long)B_*T_*Hh,
  OFF_W2F  = OFF_W1F  + (long)B_*Cc*Hh,
  OFF_U    = OFF_W2F  + (long)B_*Hh*Cc
};

// ---------------- activation ----------------
template<int ACT>
__device__ __forceinline__ float act_apply(float v) {
  if (ACT == 1) { // gelu tanh approx (jax.nn.gelu default)
    float x3 = v*v*v;
    return 0.5f*v*(1.f + tanhf(0.7978845608028654f*(v + 0.044715f*x3)));
  } else if (ACT == 2) { // silu
    return v / (1.f + expf(-v));
  }
  return v;
}

__device__ __forceinline__ float coef_f(int k) {
  float e = (float)(T_ - k);
  return (powf(0.999f, e) - powf(0.9f, e)) * (1.0f/0.099f);
}

// ================= shared GEMM core pieces =================
// LDS: As[k][m] (pad 34, b64-aligned rows), Bs[k][n] (pad 68, b128-aligned rows)

__device__ __forceinline__ void pf_load_nn(const float* __restrict__ A, const float* __restrict__ Bm,
    int M, int lda, int ldb, int m_base, int kt, int n0, int t,
    f4& ar, f4& br0, f4& br1)
{
  int arow = t >> 3, ac = (t & 7) << 2;       // 32 rows x 8 f4
  int gr = m_base + arow;
  ar = (gr < M) ? *(const f4*)&A[(long)gr*lda + kt + ac]
                : make_float4(0.f,0.f,0.f,0.f);
  int brow = t >> 4, bc = (t & 15) << 2;      // 32 rows x 16 f4 (two halves)
  br0 = *(const f4*)&Bm[(long)(kt + brow)*ldb + n0 + bc];
  br1 = *(const f4*)&Bm[(long)(kt + brow + 16)*ldb + n0 + bc];
}

__device__ __forceinline__ void pf_store_nn(float (*As)[34], float (*Bs)[68], int t,
                                            const f4& ar, const f4& br0, const f4& br1)
{
  int arow = t >> 3, ac = (t & 7) << 2;
  As[ac+0][arow] = ar.x; As[ac+1][arow] = ar.y; As[ac+2][arow] = ar.z; As[ac+3][arow] = ar.w;
  int brow = t >> 4, bc = (t & 15) << 2;
  *(f4*)&Bs[brow][bc]    = br0;
  *(f4*)&Bs[brow+16][bc] = br1;
}

__device__ __forceinline__ void compute_tile(const float (*As)[34], const float (*Bs)[68],
                                             int tx, int ty, float acc[2][4])
{
  #pragma unroll
  for (int kk = 0; kk < BK; ++kk) {
    float2 a = *(const float2*)&As[kk][2*ty];
    f4 b = *(const f4*)&Bs[kk][4*tx];
    acc[0][0] += a.x*b.x; acc[0][1] += a.x*b.y; acc[0][2] += a.x*b.z; acc[0][3] += a.x*b.w;
    acc[1][0] += a.y*b.x; acc[1][1] += a.y*b.y; acc[1][2] += a.y*b.z; acc[1][3] += a.y*b.w;
  }
}

// ================= generic NN gemm =================
// C = act(A@B [+bias]) [+rscale*res] ; DUAL: also store pre-act to Craw
template<int ACT, bool BIAS, bool RES, bool DUAL>
__global__ __launch_bounds__(256)
void gemm_f32(const float* __restrict__ A, const float* __restrict__ Bm,
              const float* __restrict__ bias, const float* __restrict__ res, float rscale,
              float* __restrict__ C, float* __restrict__ Craw,
              int M, int K, int lda, int ldb, int ldc,
              long sA, long sB, long sC, long sR)
{
  __shared__ float As[2][BK][34];
  __shared__ float Bs[2][BK][68];
  int z = blockIdx.z;
  A  += (long)z*sA; Bm += (long)z*sB; C += (long)z*sC;
  const float* resp = res + (RES ? (long)z*sR : 0);
  int tx = threadIdx.x, ty = threadIdx.y, t = ty*16+tx;
  int m_base = blockIdx.y*32, n0 = blockIdx.x*64;
  float acc[2][4] = {};
  f4 ar, br0, br1;
  pf_load_nn(A, Bm, M, lda, ldb, m_base, 0, n0, t, ar, br0, br1);
  pf_store_nn(As[0], Bs[0], t, ar, br0, br1);
  __syncthreads();
  int nt = K/BK;
  for (int kt = 0; kt < nt; ++kt) {
    int cur = kt & 1;
    bool pf = (kt+1 < nt);
    if (pf) pf_load_nn(A, Bm, M, lda, ldb, m_base, (kt+1)*BK, n0, t, ar, br0, br1);
    compute_tile(As[cur], Bs[cur], tx, ty, acc);
    __syncthreads();
    if (pf) pf_store_nn(As[cur^1], Bs[cur^1], t, ar, br0, br1);
    __syncthreads();
  }
  int c0 = n0 + 4*tx;
  #pragma unroll
  for (int i = 0; i < 2; ++i) {
    int r = m_base + 2*ty + i;
    if (r < M) {
      f4 v = make_float4(acc[i][0], acc[i][1], acc[i][2], acc[i][3]);
      if (BIAS) { v.x += bias[c0]; v.y += bias[c0+1]; v.z += bias[c0+2]; v.w += bias[c0+3]; }
      if (DUAL) *(f4*)&Craw[(long)r*ldc + c0] = v;
      v.x = act_apply<ACT>(v.x); v.y = act_apply<ACT>(v.y);
      v.z = act_apply<ACT>(v.z); v.w = act_apply<ACT>(v.w);
      if (RES) {
        f4 rv = *(const f4*)&resp[(long)r*ldc + c0];
        v.x += rscale*rv.x; v.y += rscale*rv.y; v.z += rscale*rv.z; v.w += rscale*rv.w;
      }
      *(f4*)&C[(long)r*ldc + c0] = v;
    }
  }
}

// ================= fused qkv + km + vm =================
// A = seq[z]  (TT x C).  Column segments: [0,1152) -> qkv (+bias),
// [1152,1536) -> km (suffix rows only), [1536,1920) -> vm (suffix rows only).
__global__ __launch_bounds__(256)
void qkv_kmvm_k(const float* __restrict__ seq, const float* __restrict__ c_attn_w,
                const float* __restrict__ c_attn_b, const float* __restrict__ wk,
                const float* __restrict__ wv, float* __restrict__ qkv,
                float* __restrict__ km, float* __restrict__ vm)
{
  __shared__ float As[2][BK][34];
  __shared__ float Bs[2][BK][68];
  int z = blockIdx.z;
  const float* A = seq + (long)z*TT*Cc;
  int n_global = blockIdx.x*64;
  const float* Bm; const float* bias = nullptr;
  float* C; int ldb, ldc, n0; bool suf = false;
  if (n_global < 3*Cc)            { Bm = c_attn_w; ldb = 3*Cc; n0 = n_global;        C = qkv + (long)z*TT*3*Cc; ldc = 3*Cc; bias = c_attn_b; }
  else if (n_global < 3*Cc + Cc)  { Bm = wk;       ldb = Cc;   n0 = n_global - 3*Cc; C = km  + (long)z*T_*Cc;   ldc = Cc;   suf = true; }
  else                            { Bm = wv;       ldb = Cc;   n0 = n_global - 4*Cc; C = vm  + (long)z*T_*Cc;   ldc = Cc;   suf = true; }
  int tx = threadIdx.x, ty = threadIdx.y, t = ty*16+tx;
  int m_base = blockIdx.y*32;
  float acc[2][4] = {};
  f4 ar, br0, br1;
  pf_load_nn(A, Bm, TT, Cc, ldb, m_base, 0, n0, t, ar, br0, br1);
  pf_store_nn(As[0], Bs[0], t, ar, br0, br1);
  __syncthreads();
  const int nt = Cc/BK;
  for (int kt = 0; kt < nt; ++kt) {
    int cur = kt & 1;
    bool pf = (kt+1 < nt);
    if (pf) pf_load_nn(A, Bm, TT, Cc, ldb, m_base, (kt+1)*BK, n0, t, ar, br0, br1);
    compute_tile(As[cur], Bs[cur], tx, ty, acc);
    __syncthreads();
    if (pf) pf_store_nn(As[cur^1], Bs[cur^1], t, ar, br0, br1);
    __syncthreads();
  }
  int c0 = n0 + 4*tx;
  #pragma unroll
  for (int i = 0; i < 2; ++i) {
    int r = m_base + 2*ty + i;
    if (r < TT) {
      f4 v = make_float4(acc[i][0], acc[i][1], acc[i][2], acc[i][3]);
      if (bias) { v.x += bias[c0]; v.y += bias[c0+1]; v.z += bias[c0+2]; v.w += bias[c0+3]; }
      if (suf) {
        if (r >= PL_) *(f4*)&C[(long)(r-PL_)*ldc + c0] = v;
      } else {
        *(f4*)&C[(long)r*ldc + c0] = v;
      }
    }
  }
}

// ================= dh = (err @ W2^T) * silu'(hh) =================
__global__ __launch_bounds__(256)
void gemm_bt_dsilu2(const float* __restrict__ E, const float* __restrict__ W2,
                    const float* __restrict__ HH, float* __restrict__ DH,
                    int M, int K, int lda, int ldb, int ldc)
{
  __shared__ float As[2][BK][34];
  __shared__ float Bs[2][BK][68];
  int tx = threadIdx.x, ty = threadIdx.y, t = ty*16+tx;
  int m_base = blockIdx.y*32, n0 = blockIdx.x*64;
  float acc[2][4] = {};
  f4 ar, br0, br1;
  auto load = [&](int kt) {
    int arow = t >> 3, ac = (t & 7) << 2;
    int gr = m_base + arow;
    ar = (gr < M) ? *(const f4*)&E[(long)gr*lda + kt + ac] : make_float4(0.f,0.f,0.f,0.f);
    int nrow = t >> 3, kc = (t & 7) << 2;     // 64 n-rows via two halves
    br0 = *(const f4*)&W2[(long)(n0 + nrow)*ldb + kt + kc];
    br1 = *(const f4*)&W2[(long)(n0 + nrow + 32)*ldb + kt + kc];
  };
  auto store = [&](float (*Asb)[34], float (*Bsb)[68]) {
    int arow = t >> 3, ac = (t & 7) << 2;
    Asb[ac+0][arow] = ar.x; Asb[ac+1][arow] = ar.y; Asb[ac+2][arow] = ar.z; Asb[ac+3][arow] = ar.w;
    int nrow = t >> 3, kc = (t & 7) << 2;
    Bsb[kc+0][nrow] = br0.x; Bsb[kc+1][nrow] = br0.y; Bsb[kc+2][nrow] = br0.z; Bsb[kc+3][nrow] = br0.w;
    Bsb[kc+0][nrow+32] = br1.x; Bsb[kc+1][nrow+32] = br1.y; Bsb[kc+2][nrow+32] = br1.z; Bsb[kc+3][nrow+32] = br1.w;
  };
  load(0); store(As[0], Bs[0]);
  __syncthreads();
  int nt = K/BK;
  for (int kt = 0; kt < nt; ++kt) {
    int cur = kt & 1;
    bool pf = (kt+1 < nt);
    if (pf) load((kt+1)*BK);
    compute_tile(As[cur], Bs[cur], tx, ty, acc);
    __syncthreads();
    if (pf) store(As[cur^1], Bs[cur^1]);
    __syncthreads();
  }
  int c0 = n0 + 4*tx;
  #pragma unroll
  for (int i = 0; i < 2; ++i) {
    int r = m_base + 2*ty + i;
    if (r < M) {
      f4 h = *(const f4*)&HH[(long)r*ldc + c0];
      f4 v;
      float sg;
      sg = 1.f/(1.f+expf(-h.x)); v.x = acc[i][0]*(sg*(1.f + h.x*(1.f-sg)));
      sg = 1.f/(1.f+expf(-h.y)); v.y = acc[i][1]*(sg*(1.f + h.y*(1.f-sg)));
      sg = 1.f/(1.f+expf(-h.z)); v.z = acc[i][2]*(sg*(1.f + h.z*(1.f-sg)));
      sg = 1.f/(1.f+expf(-h.w)); v.w = acc[i][3]*(sg*(1.f + h.w*(1.f-sg)));
      *(f4*)&DH[(long)r*ldc + c0] = v;
    }
  }
}

// ================= weight update: Cout = dpow*W0 + scale * sum_k coef[k]*A[k,m]*B[k,n] =================
// A [K x M] row-major per batch, B [K x N] row-major per batch, W0 shared. M,N multiples of 32/64, K=T_.
__global__ __launch_bounds__(256)
void gemm_atc2(const float* __restrict__ A, const float* __restrict__ Bm,
               const float* __restrict__ W0, float* __restrict__ Cout,
               int Mdim, int N, int lda, int ldb,
               long sA, long sB, long sC, float scale, float dpow)
{
  __shared__ float As[2][BK][34];
  __shared__ float Bs[2][BK][68];
  int z = blockIdx.z;
  A += (long)z*sA; Bm += (long)z*sB; Cout += (long)z*sC;
  int tx = threadIdx.x, ty = threadIdx.y, t = ty*16+tx;
  int m_base = blockIdx.y*32, n0 = blockIdx.x*64;
  float acc[2][4] = {};
  f4 ar, br0, br1;
  auto load = [&](int kt) {
    int krow = t >> 3, mc = (t & 7) << 2;
    ar = *(const f4*)&A[(long)(kt + krow)*lda + m_base + mc];
    float cf = coef_f(kt + krow);
    ar.x *= cf; ar.y *= cf; ar.z *= cf; ar.w *= cf;
    int brow = t >> 4, bc = (t & 15) << 2;
    br0 = *(const f4*)&Bm[(long)(kt + brow)*ldb + n0 + bc];
    br1 = *(const f4*)&Bm[(long)(kt + brow + 16)*ldb + n0 + bc];
  };
  auto store = [&](float (*Asb)[34], float (*Bsb)[68]) {
    int krow = t >> 3, mc = (t & 7) << 2;
    Asb[krow][mc+0] = ar.x; Asb[krow][mc+1] = ar.y; Asb[krow][mc+2] = ar.z; Asb[krow][mc+3] = ar.w;
    int brow = t >> 4, bc = (t & 15) << 2;
    *(f4*)&Bsb[brow][bc]    = br0;
    *(f4*)&Bsb[brow+16][bc] = br1;
  };
  load(0); store(As[0], Bs[0]);
  __syncthreads();
  const int nt = T_/BK;
  for (int kt = 0; kt < nt; ++kt) {
    int cur = kt & 1;
    bool pf = (kt+1 < nt);
    if (pf) load((kt+1)*BK);
    compute_tile(As[cur], Bs[cur], tx, ty, acc);
    __syncthreads();
    if (pf) store(As[cur^1], Bs[cur^1]);
    __syncthreads();
  }
  int c0 = n0 + 4*tx;
  #pragma unroll
  for (int i = 0; i < 2; ++i) {
    int r = m_base + 2*ty + i;
    f4 w = *(const f4*)&W0[(long)r*N + c0];
    f4 v = make_float4(dpow*w.x + scale*acc[i][0], dpow*w.y + scale*acc[i][1],
                       dpow*w.z + scale*acc[i][2], dpow*w.w + scale*acc[i][3]);
    *(f4*)&Cout[(long)r*N + c0] = v;
  }
}

// ================= retr2: seq[b][P_+r] = hid @ mem_w2 (both batches) =================
__global__ __launch_bounds__(256)
void retr2_k(const float* __restrict__ hid, const float* __restrict__ W2,
             float* __restrict__ seq)
{
  __shared__ float As[2][BK][34];
  __shared__ float Bs[2][BK][68];
  int tx = threadIdx.x, ty = threadIdx.y, t = ty*16+tx;
  int n0 = blockIdx.x*64;
  float acc[2][4] = {};
  f4 ar, br0, br1;
  pf_load_nn(hid, W2, M_, Hh, Cc, 0, 0, n0, t, ar, br0, br1);
  pf_store_nn(As[0], Bs[0], t, ar, br0, br1);
  __syncthreads();
  const int nt = Hh/BK;
  for (int kt = 0; kt < nt; ++kt) {
    int cur = kt & 1;
    bool pf = (kt+1 < nt);
    if (pf) pf_load_nn(hid, W2, M_, Hh, Cc, 0, (kt+1)*BK, n0, t, ar, br0, br1);
    compute_tile(As[cur], Bs[cur], tx, ty, acc);
    __syncthreads();
    if (pf) pf_store_nn(As[cur^1], Bs[cur^1], t, ar, br0, br1);
    __syncthreads();
  }
  int c0 = n0 + 4*tx;
  #pragma unroll
  for (int i = 0; i < 2; ++i) {
    int r = 2*ty + i;
    if (r < M_) {
      f4 v = make_float4(acc[i][0], acc[i][1], acc[i][2], acc[i][3]);
      *(f4*)&seq[((long)(P_ + r))*Cc + c0] = v;
      *(f4*)&seq[((long)(TT + P_ + r))*Cc + c0] = v;
    }
  }
}

// ================= LN1 -> seq suffix (+persist prefix copy) =================
__global__ __launch_bounds__(384)
void ln1_seq_k(const float* __restrict__ x, const float* __restrict__ g,
               const float* __restrict__ bvec, const float* __restrict__ persist,
               float* __restrict__ seq)
{
  int row = blockIdx.x;
  int tid = threadIdx.x;
  if (row >= B_*T_) {
    int b = row - B_*T_;
    for (int r = 0; r < P_; ++r)
      seq[((long)b*TT + r)*Cc + tid] = persist[r*Cc + tid];
    return;
  }
  float v = x[(long)row*Cc + tid];
  int lane = tid & 63, wid = tid >> 6;
  __shared__ float red[6];
  __shared__ float mu_s, rstd_s;
  float s = v;
  #pragma unroll
  for (int off = 32; off; off >>= 1) s += __shfl_down(s, off);
  if (lane == 0) red[wid] = s;
  __syncthreads();
  if (tid == 0) { float tt = 0; for (int i = 0; i < 6; ++i) tt += red[i]; mu_s = tt / (float)Cc; }
  __syncthreads();
  float d = v - mu_s;
  float sq = d*d;
  #pragma unroll
  for (int off = 32; off; off >>= 1) sq += __shfl_down(sq, off);
  if (lane == 0) red[wid] = sq;
  __syncthreads();
  if (tid == 0) { float tt = 0; for (int i = 0; i < 6; ++i) tt += red[i]; rstd_s = rsqrtf(tt / (float)Cc + 1e-5f); }
  __syncthreads();
  int b = row / T_, tr = row % T_;
  seq[((long)b*TT + PL_ + tr)*Cc + tid] = d * rstd_s * g[tid] + bvec[tid];
}

// ================= LN2 =================
__global__ __launch_bounds__(384)
void ln2_k(const float* __restrict__ x, const float* __restrict__ g,
           const float* __restrict__ bvec, float* __restrict__ out)
{
  int row = blockIdx.x;
  int tid = threadIdx.x;
  float v = x[(long)row*Cc + tid];
  int lane = tid & 63, wid = tid >> 6;
  __shared__ float red[6];
  __shared__ float mu_s, rstd_s;
  float s = v;
  #pragma unroll
  for (int off = 32; off; off >>= 1) s += __shfl_down(s, off);
  if (lane == 0) red[wid] = s;
  __syncthreads();
  if (tid == 0) { float tt = 0; for (int i = 0; i < 6; ++i) tt += red[i]; mu_s = tt / (float)Cc; }
  __syncthreads();
  float d = v - mu_s;
  float sq = d*d;
  #pragma unroll
  for (int off = 32; off; off >>= 1) sq += __shfl_down(sq, off);
  if (lane == 0) red[wid] = sq;
  __syncthreads();
  if (tid == 0) { float tt = 0; for (int i = 0; i < 6; ++i) tt += red[i]; rstd_s = rsqrtf(tt / (float)Cc + 1e-5f); }
  __syncthreads();
  out[(long)row*Cc + tid] = d * rstd_s * g[tid] + bvec[tid];
}

// ================= attention: one wave per (b, h, suffix q-row) =================
__global__ __launch_bounds__(64)
void attn_k(const float* __restrict__ qkv, float* __restrict__ yb)
{
  const int Cq = 3*Cc;
  int lane = threadIdx.x;
  int qr = PL_ + blockIdx.x;
  int h  = blockIdx.y;
  int b  = blockIdx.z;
  const float* base = qkv + (long)(b*TT)*Cq;
  __shared__ float qs[HD];
  __shared__ float p[TT];
  qs[lane] = base[(long)qr*Cq + h*HD + lane];
  __syncthreads();
  float mloc = -1e30f;
  for (int k = lane; k < TT; k += 64) {
    float s = -1e30f;
    if (k <= qr) {
      const float* kp = base + (long)k*Cq + Cc + h*HD;
      float acc = 0.f;
      #pragma unroll
      for (int d2 = 0; d2 < HD; ++d2) acc += qs[d2]*kp[d2];
      s = acc * 0.125f;
    }
    p[k] = s;
    mloc = fmaxf(mloc, s);
  }
  #pragma unroll
  for (int off = 32; off; off >>= 1) mloc = fmaxf(mloc, __shfl_xor(mloc, off));
  float ssum = 0.f;
  for (int k = lane; k < TT; k += 64) {
    float e = (k <= qr) ? expf(p[k] - mloc) : 0.f;
    p[k] = e;
    ssum += e;
  }
  #pragma unroll
  for (int off = 32; off; off >>= 1) ssum += __shfl_xor(ssum, off);
  __syncthreads();
  float inv = 1.f / ssum;
  float acc = 0.f;
  for (int k = 0; k <= qr; ++k)
    acc += p[k] * base[(long)k*Cq + 2*Cc + h*HD + lane];
  yb[((long)(b*T_ + blockIdx.x))*Cc + h*HD + lane] = acc * inv;
}

// ---------------- launch ----------------
extern "C" void kernel_launch(void* const* d_in, const int* in_sizes, int n_in,
                              void* d_out, int out_size, void* d_ws, size_t ws_size,
                              hipStream_t stream)
{
  const float* x         = (const float*)d_in[0];
  const float* c_attn_w  = (const float*)d_in[1];
  const float* c_attn_b  = (const float*)d_in[2];
  const float* c_proj_w  = (const float*)d_in[3];
  const float* c_proj_b  = (const float*)d_in[4];
  const float* ln1_g     = (const float*)d_in[5];
  const float* ln1_b     = (const float*)d_in[6];
  const float* ln2_g     = (const float*)d_in[7];
  const float* ln2_b     = (const float*)d_in[8];
  const float* fc_w      = (const float*)d_in[9];
  const float* fc_b      = (const float*)d_in[10];
  const float* pr_w      = (const float*)d_in[11];
  const float* pr_b      = (const float*)d_in[12];
  const float* mem_w1    = (const float*)d_in[13];
  const float* mem_w2    = (const float*)d_in[14];
  const float* wk        = (const float*)d_in[15];
  const float* wv        = (const float*)d_in[16];
  const float* mem_q     = (const float*)d_in[17];
  const float* persist   = (const float*)d_in[18];

  float* ws   = (float*)d_ws;
  float* seq  = ws + OFF_SEQ;
  float* hid  = ws + OFF_HID;
  float* qkv  = ws + OFF_QKV;
  float* yb   = ws + OFF_Y;
  float* h1   = ws + OFF_H1;
  float* h2n  = ws + OFF_H2N;
  float* fco  = ws + OFF_FC;
  float* h2   = ws + OFF_H2;
  float* km   = ws + OFF_KM;
  float* vm   = ws + OFF_VM;
  float* hh   = ws + OFF_HH;
  float* ab   = ws + OFF_A;
  float* errb = ws + OFF_ERR;
  float* dhb  = ws + OFF_DH;
  float* w1f  = ws + OFF_W1F;
  float* w2f  = ws + OFF_W2F;
  float* ub   = ws + OFF_U;
  float* outp = (float*)d_out;

  dim3 tb(16, 16);
  const float dpow  = powf(0.999f, 128.f);
  const float scale = -0.001f;

  // 1. xn -> seq suffix rows; persist -> seq prefix rows 0..3
  ln1_seq_k<<<B_*T_ + B_, Cc, 0, stream>>>(x, ln1_g, ln1_b, persist, seq);

  // 2. hid = silu(mem_q @ mem_w1)
  gemm_f32<2,false,false,false><<<dim3(Hh/64, 1, 1), tb, 0, stream>>>(
      mem_q, mem_w1, nullptr, nullptr, 0.f, hid, nullptr,
      M_, Cc, Cc, Hh, Hh, 0,0,0,0);

  // 3. seq rows 4..19 (both batches) = hid @ mem_w2
  retr2_k<<<dim3(Cc/64, 1, 1), tb, 0, stream>>>(hid, mem_w2, seq);

  // 4. fused qkv / km / vm
  qkv_kmvm_k<<<dim3((3*Cc + 2*Cc)/64, cdiv(TT,32), B_), tb, 0, stream>>>(
      seq, c_attn_w, c_attn_b, wk, wv, qkv, km, vm);

  // 5. attention
  attn_k<<<dim3(T_, NH_, B_), 64, 0, stream>>>(qkv, yb);

  // 6. h1 = x + yb @ c_proj_w + b
  gemm_f32<0,true,true,false><<<dim3(Cc/64, (B_*T_)/32, 1), tb, 0, stream>>>(
      yb, c_proj_w, c_proj_b, x, 1.f, h1, nullptr,
      B_*T_, Cc, Cc, Cc, Cc, 0,0,0,0);

  // 7. h2n = LN2(h1)
  ln2_k<<<B_*T_, Cc, 0, stream>>>(h1, ln2_g, ln2_b, h2n);

  // 8. fco = gelu(h2n @ fc_w + b)
  gemm_f32<1,true,false,false><<<dim3((4*Cc)/64, (B_*T_)/32, 1), tb, 0, stream>>>(
      h2n, fc_w, fc_b, nullptr, 0.f, fco, nullptr,
      B_*T_, Cc, Cc, 4*Cc, 4*Cc, 0,0,0,0);

  // 9. h2 = h1 + fco @ pr_w + b
  gemm_f32<0,true,true,false><<<dim3(Cc/64, (B_*T_)/32, 1), tb, 0, stream>>>(
      fco, pr_w, pr_b, h1, 1.f, h2, nullptr,
      B_*T_, 4*Cc, 4*Cc, Cc, Cc, 0,0,0,0);

  // 10. hh = km @ mem_w1 ; ab = silu(hh)   (dual store)
  gemm_f32<2,false,false,true><<<dim3(Hh/64, (B_*T_)/32, 1), tb, 0, stream>>>(
      km, mem_w1, nullptr, nullptr, 0.f, ab, hh,
      B_*T_, Cc, Cc, Hh, Hh, 0,0,0,0);

  // 11. err = ab @ mem_w2 - vm
  gemm_f32<0,false,true,false><<<dim3(Cc/64, (B_*T_)/32, 1), tb, 0, stream>>>(
      ab, mem_w2, nullptr, vm, -1.f, errb, nullptr,
      B_*T_, Hh, Hh, Cc, Cc, 0,0,0,0);

  // 12. dh = (err @ mem_w2^T) * silu'(hh)
  gemm_bt_dsilu2<<<dim3(Hh/64, (B_*T_)/32, 1), tb, 0, stream>>>(
      errb, mem_w2, hh, dhb, B_*T_, Cc, Cc, Cc, Hh);

  // 13. w1f[b] = dpow*mem_w1 + scale * sum_t coef[t]*km^T dh
  gemm_atc2<<<dim3(Hh/64, Cc/32, B_), tb, 0, stream>>>(
      km, dhb, mem_w1, w1f, Cc, Hh, Cc, Hh,
      (long)T_*Cc, (long)T_*Hh, (long)Cc*Hh, scale, dpow);

  // 14. w2f[b] = dpow*mem_w2 + scale * sum_t coef[t]*ab^T err
  gemm_atc2<<<dim3(Cc/64, Hh/32, B_), tb, 0, stream>>>(
      ab, errb, mem_w2, w2f, Hh, Cc, Hh, Cc,
      (long)T_*Hh, (long)T_*Cc, (long)Hh*Cc, scale, dpow);

  // 15. ub = silu(h2 @ w1f)  (z-batched)
  gemm_f32<2,false,false,false><<<dim3(Hh/64, T_/32, B_), tb, 0, stream>>>(
      h2, w1f, nullptr, nullptr, 0.f, ub, nullptr,
      T_, Cc, Cc, Hh, Hh,
      (long)T_*Cc, (long)Cc*Hh, (long)T_*Hh, 0);

  // 16. out = h2 + ub @ w2f  (z-batched)
  gemm_f32<0,false,true,false><<<dim3(Cc/64, T_/32, B_), tb, 0, stream>>>(
      ub, w2f, nullptr, h2, 1.f, outp, nullptr,
      T_, Hh, Hh, Cc, Cc,
      (long)T_*Hh, (long)Hh*Cc, (long)T_*Cc, (long)T_*Cc);
}

// Round 3
// 269.525 us; speedup vs baseline: 1.8982x; 1.0434x over previous
//
#include <hip/hip_runtime.h>
#include <math.h>

#define B_ 2
#define T_ 128
#define Cc 384
#define NH_ 6
#define HD 64
#define Hh 768
#define P_ 4
#define M_ 16
#define PL_ 20
#define TT 148

typedef short short8 __attribute__((ext_vector_type(8)));
typedef float f32x4 __attribute__((ext_vector_type(4)));

static inline int cdiv(int a, int b) { return (a + b - 1) / b; }

// ---------- helpers ----------
__device__ __forceinline__ unsigned short f2bf(float f) {
  unsigned int u = __float_as_uint(f);
  u += 0x7FFFu + ((u >> 16) & 1u);
  return (unsigned short)(u >> 16);
}
__device__ __forceinline__ float siluf(float v) { return v / (1.f + expf(-v)); }
__device__ __forceinline__ float geluf(float v) {
  float x3 = v*v*v;
  return 0.5f*v*(1.f + tanhf(0.7978845608028654f*(v + 0.044715f*x3)));
}
template<int ACT> __device__ __forceinline__ float act_apply(float v) {
  if (ACT == 1) return geluf(v);
  if (ACT == 2) return siluf(v);
  return v;
}
__device__ __forceinline__ float coef_f(int k) {
  float e = (float)(T_ - k);
  return (powf(0.999f, e) - powf(0.9f, e)) * (1.0f/0.099f);
}
__device__ __forceinline__ void st_tr4(unsigned short* dst, float v0, float v1, float v2, float v3) {
  union { unsigned short u[4]; uint2 d; } q;
  q.u[0]=f2bf(v0); q.u[1]=f2bf(v1); q.u[2]=f2bf(v2); q.u[3]=f2bf(v3);
  *(uint2*)dst = q.d;
}

// ---------- MFMA core: wave computes 32x64 tile, A [M][K] bf16, BT [N][K] bf16 ----------
template<int KT>
__device__ __forceinline__ void run_mfma(const unsigned short* __restrict__ A,
    const unsigned short* __restrict__ BT, long r0, long r1,
    long c0, long c1, long c2, long c3, int kg, f32x4 acc[2][4])
{
  const long K = (long)KT*32;
  const unsigned short* pa0 = A + r0*K + kg*8;
  const unsigned short* pa1 = A + r1*K + kg*8;
  const unsigned short* pb0 = BT + c0*K + kg*8;
  const unsigned short* pb1 = BT + c1*K + kg*8;
  const unsigned short* pb2 = BT + c2*K + kg*8;
  const unsigned short* pb3 = BT + c3*K + kg*8;
  short8 a0 = *(const short8*)pa0, a1 = *(const short8*)pa1;
  short8 b0 = *(const short8*)pb0, b1 = *(const short8*)pb1;
  short8 b2 = *(const short8*)pb2, b3 = *(const short8*)pb3;
  #pragma unroll
  for (int t = 0; t < KT; ++t) {
    short8 xa0=a0, xa1=a1, xb0=b0, xb1=b1, xb2=b2, xb3=b3;
    if (t+1 < KT) {
      int o = (t+1)*32;
      a0 = *(const short8*)(pa0+o); a1 = *(const short8*)(pa1+o);
      b0 = *(const short8*)(pb0+o); b1 = *(const short8*)(pb1+o);
      b2 = *(const short8*)(pb2+o); b3 = *(const short8*)(pb3+o);
    }
    acc[0][0] = __builtin_amdgcn_mfma_f32_16x16x32_bf16(xa0, xb0, acc[0][0], 0,0,0);
    acc[0][1] = __builtin_amdgcn_mfma_f32_16x16x32_bf16(xa0, xb1, acc[0][1], 0,0,0);
    acc[0][2] = __builtin_amdgcn_mfma_f32_16x16x32_bf16(xa0, xb2, acc[0][2], 0,0,0);
    acc[0][3] = __builtin_amdgcn_mfma_f32_16x16x32_bf16(xa0, xb3, acc[0][3], 0,0,0);
    acc[1][0] = __builtin_amdgcn_mfma_f32_16x16x32_bf16(xa1, xb0, acc[1][0], 0,0,0);
    acc[1][1] = __builtin_amdgcn_mfma_f32_16x16x32_bf16(xa1, xb1, acc[1][1], 0,0,0);
    acc[1][2] = __builtin_amdgcn_mfma_f32_16x16x32_bf16(xa1, xb2, acc[1][2], 0,0,0);
    acc[1][3] = __builtin_amdgcn_mfma_f32_16x16x32_bf16(xa1, xb3, acc[1][3], 0,0,0);
  }
}

#define GEMM_COORDS(Mval)                                \
  int l = threadIdx.x & 63, w = threadIdx.x >> 6;        \
  int lr = l & 15, kg = l >> 4;                          \
  int mBase = blockIdx.y*64 + (w>>1)*32;                 \
  int nBase = blockIdx.x*128 + (w&1)*64;                 \
  long r0 = (long)min(mBase + lr, (Mval)-1);             \
  long r1 = (long)min(mBase + 16 + lr, (Mval)-1);        \
  long c0 = nBase + lr;

// ---------- generic bf16 MFMA gemm with epilogue flags ----------
template<int KT, int ACT, bool BIAS, bool RES, bool STF, bool STB, bool STTR>
__global__ __launch_bounds__(256)
void gemm_k(const unsigned short* __restrict__ A, const unsigned short* __restrict__ BT,
            const float* __restrict__ bias, const float* __restrict__ res, float rscale,
            float* __restrict__ outF, unsigned short* __restrict__ outB,
            unsigned short* __restrict__ outT,
            int M, int N, long sA, long sB, long sOut, long sR)
{
  int z = blockIdx.z;
  const unsigned short* Az = A + (long)z*sA;
  const unsigned short* Bz = BT + (long)z*sB;
  GEMM_COORDS(M);
  f32x4 acc[2][4] = {};
  run_mfma<KT>(Az, Bz, r0, r1, c0, c0+16, c0+32, c0+48, kg, acc);
  #pragma unroll
  for (int i = 0; i < 2; ++i) {
    int ro = mBase + i*16 + kg*4;
    #pragma unroll
    for (int j = 0; j < 4; ++j) {
      int col = nBase + j*16 + lr;
      float bv = BIAS ? bias[col] : 0.f;
      float v4[4];
      #pragma unroll
      for (int jj = 0; jj < 4; ++jj) {
        int r = ro + jj;
        float v = acc[i][j][jj] + bv;
        v = act_apply<ACT>(v);
        if (RES && r < M) v += rscale * res[(long)z*sR + (long)r*N + col];
        v4[jj] = v;
        if (r < M) {
          if (STF) outF[(long)z*sOut + (long)r*N + col] = v;
          if (STB) outB[(long)z*sOut + (long)r*N + col] = f2bf(v);
        }
      }
      if (STTR && ro < M) { // [z][N][128] transposed, rows-per-batch=128
        int zz = ro >> 7, t0 = ro & 127;
        st_tr4(&outT[((long)zz*N + col)*128 + t0], v4[0], v4[1], v4[2], v4[3]);
      }
    }
  }
}

// ---------- fused qkv/km/vm ----------
__global__ __launch_bounds__(256)
void qkv_k(const unsigned short* __restrict__ seqb, const unsigned short* __restrict__ cattnT,
           const unsigned short* __restrict__ wkT, const unsigned short* __restrict__ wvT,
           const float* __restrict__ cab, float* __restrict__ qkv,
           unsigned short* __restrict__ km, unsigned short* __restrict__ kmTc,
           float* __restrict__ vm)
{
  int nb = blockIdx.x * 128;
  const unsigned short* BT; int n0, seg;
  if (nb < 1152)      { BT = cattnT; n0 = nb;        seg = 0; }
  else if (nb < 1536) { BT = wkT;    n0 = nb - 1152; seg = 1; }
  else                { BT = wvT;    n0 = nb - 1536; seg = 2; }
  int l = threadIdx.x & 63, w = threadIdx.x >> 6;
  int lr = l & 15, kg = l >> 4;
  int mBase = blockIdx.y*64 + (w>>1)*32;
  int nBase = n0 + (w&1)*64;
  long r0 = (long)min(mBase + lr, 295);
  long r1 = (long)min(mBase + 16 + lr, 295);
  long c0 = nBase + lr;
  f32x4 acc[2][4] = {};
  run_mfma<12>(seqb, BT, r0, r1, c0, c0+16, c0+32, c0+48, kg, acc);
  #pragma unroll
  for (int i = 0; i < 2; ++i) {
    int ro = mBase + i*16 + kg*4;
    #pragma unroll
    for (int j = 0; j < 4; ++j) {
      int col = nBase + j*16 + lr;
      if (seg == 0) {
        float bv = cab[col];
        #pragma unroll
        for (int jj = 0; jj < 4; ++jj) {
          int r = ro + jj;
          if (r < 296) qkv[(long)r*1152 + col] = acc[i][j][jj] + bv;
        }
      } else if (seg == 1) {
        #pragma unroll
        for (int jj = 0; jj < 4; ++jj) {
          int r = ro + jj;
          if (r < 296) {
            int z = r/148, t = r%148 - 20;
            if (t >= 0) km[((long)z*128 + t)*384 + col] = f2bf(acc[i][j][jj]);
          }
        }
        int z = ro/148, t0 = ro%148 - 20;
        if (ro < 296 && t0 >= 0)
          st_tr4(&kmTc[((long)z*384 + col)*128 + t0],
                 acc[i][j][0]*coef_f(t0),   acc[i][j][1]*coef_f(t0+1),
                 acc[i][j][2]*coef_f(t0+2), acc[i][j][3]*coef_f(t0+3));
      } else {
        #pragma unroll
        for (int jj = 0; jj < 4; ++jj) {
          int r = ro + jj;
          if (r < 296) {
            int z = r/148, t = r%148 - 20;
            if (t >= 0) vm[((long)z*128 + t)*384 + col] = acc[i][j][jj];
          }
        }
      }
    }
  }
}

// ---------- hh = km@w1 : store hh f32, ab=silu bf16, abTc=silu*coef transposed ----------
__global__ __launch_bounds__(256)
void hh_k(const unsigned short* __restrict__ km, const unsigned short* __restrict__ w1tr,
          float* __restrict__ hh, unsigned short* __restrict__ ab, unsigned short* __restrict__ abTc)
{
  GEMM_COORDS(256);
  f32x4 acc[2][4] = {};
  run_mfma<12>(km, w1tr, r0, r1, c0, c0+16, c0+32, c0+48, kg, acc);
  #pragma unroll
  for (int i = 0; i < 2; ++i) {
    int ro = mBase + i*16 + kg*4;
    #pragma unroll
    for (int j = 0; j < 4; ++j) {
      int col = nBase + j*16 + lr;
      float s4[4];
      #pragma unroll
      for (int jj = 0; jj < 4; ++jj) {
        int r = ro + jj;
        float raw = acc[i][j][jj];
        hh[(long)r*768 + col] = raw;
        float s = siluf(raw);
        s4[jj] = s;
        ab[(long)r*768 + col] = f2bf(s);
      }
      int zz = ro >> 7, t0 = ro & 127;
      st_tr4(&abTc[((long)zz*768 + col)*128 + t0],
             s4[0]*coef_f(t0), s4[1]*coef_f(t0+1), s4[2]*coef_f(t0+2), s4[3]*coef_f(t0+3));
    }
  }
}

// ---------- dh = (err @ W2^T) * dsilu(hh) -> dhT transposed bf16 only ----------
__global__ __launch_bounds__(256)
void dh_k(const unsigned short* __restrict__ errB, const unsigned short* __restrict__ w2pl,
          const float* __restrict__ hh, unsigned short* __restrict__ dhT)
{
  GEMM_COORDS(256);
  f32x4 acc[2][4] = {};
  run_mfma<12>(errB, w2pl, r0, r1, c0, c0+16, c0+32, c0+48, kg, acc);
  #pragma unroll
  for (int i = 0; i < 2; ++i) {
    int ro = mBase + i*16 + kg*4;
    #pragma unroll
    for (int j = 0; j < 4; ++j) {
      int col = nBase + j*16 + lr;
      float v4[4];
      #pragma unroll
      for (int jj = 0; jj < 4; ++jj) {
        int r = ro + jj;
        float h = hh[(long)r*768 + col];
        float sg = 1.f/(1.f + expf(-h));
        v4[jj] = acc[i][j][jj] * (sg*(1.f + h*(1.f - sg)));
      }
      int zz = ro >> 7, t0 = ro & 127;
      st_tr4(&dhT[((long)zz*768 + col)*128 + t0], v4[0], v4[1], v4[2], v4[3]);
    }
  }
}

// ---------- weight update: outT[z][n][m] = dpow*W0[m][n] + scale*acc ----------
__global__ __launch_bounds__(256)
void wupd_k(const unsigned short* __restrict__ A, const unsigned short* __restrict__ BT,
            const float* __restrict__ W0, unsigned short* __restrict__ outT,
            int M, int N, float scale, float dpow)
{
  int z = blockIdx.z;
  const unsigned short* Az = A + (long)z*M*128;
  const unsigned short* Bz = BT + (long)z*N*128;
  unsigned short* Oz = outT + (long)z*M*N;
  GEMM_COORDS(M);
  f32x4 acc[2][4] = {};
  run_mfma<4>(Az, Bz, r0, r1, c0, c0+16, c0+32, c0+48, kg, acc);
  #pragma unroll
  for (int i = 0; i < 2; ++i) {
    int ro = mBase + i*16 + kg*4;
    #pragma unroll
    for (int j = 0; j < 4; ++j) {
      int col = nBase + j*16 + lr;
      float v4[4];
      #pragma unroll
      for (int jj = 0; jj < 4; ++jj) {
        int r = ro + jj;
        v4[jj] = dpow*W0[(long)r*N + col] + scale*acc[i][j][jj];
      }
      st_tr4(&Oz[(long)col*M + ro], v4[0], v4[1], v4[2], v4[3]);
    }
  }
}

// ---------- retr -> seq rows 4..19 (both batches) ----------
__global__ __launch_bounds__(256)
void mem2_k(const unsigned short* __restrict__ hid, const unsigned short* __restrict__ w2tr,
            unsigned short* __restrict__ seqb)
{
  GEMM_COORDS(16);
  f32x4 acc[2][4] = {};
  run_mfma<24>(hid, w2tr, r0, r1, c0, c0+16, c0+32, c0+48, kg, acc);
  #pragma unroll
  for (int i = 0; i < 2; ++i) {
    int ro = mBase + i*16 + kg*4;
    #pragma unroll
    for (int j = 0; j < 4; ++j) {
      int col = nBase + j*16 + lr;
      #pragma unroll
      for (int jj = 0; jj < 4; ++jj) {
        int r = ro + jj;
        if (r < 16) {
          unsigned short v = f2bf(acc[i][j][jj]);
          seqb[(long)(P_ + r)*384 + col] = v;
          seqb[(long)(TT + P_ + r)*384 + col] = v;
        }
      }
    }
  }
}

// ---------- weight/input conversion (one kernel) ----------
__global__ void convert_k(
    const float* __restrict__ c_attn_w, const float* __restrict__ c_proj_w,
    const float* __restrict__ wk, const float* __restrict__ wv,
    const float* __restrict__ fc_w, const float* __restrict__ pr_w,
    const float* __restrict__ mw1, const float* __restrict__ mw2,
    const float* __restrict__ mem_q, const float* __restrict__ persist,
    unsigned short* __restrict__ cattnT, unsigned short* __restrict__ cprojT,
    unsigned short* __restrict__ wkT, unsigned short* __restrict__ wvT,
    unsigned short* __restrict__ fcT, unsigned short* __restrict__ prT,
    unsigned short* __restrict__ w1tr, unsigned short* __restrict__ w2tr,
    unsigned short* __restrict__ w2pl, unsigned short* __restrict__ memq,
    unsigned short* __restrict__ seqb)
{
  const long S_cattn = 1152L*384, S_sq = 384L*384, S_fc = 1536L*384, S_pr = 384L*1536,
             S_w1 = 768L*384, S_w2 = 384L*768, S_w2p = 768L*384, S_mq = 16L*384, S_ps = 4L*384;
  const long total = S_cattn + 3*S_sq + S_fc + S_pr + S_w1 + S_w2 + S_w2p + S_mq + S_ps;
  for (long i = (long)blockIdx.x*blockDim.x + threadIdx.x; i < total;
       i += (long)gridDim.x*blockDim.x) {
    long li = i;
    if (li < S_cattn) { long n = li/384, k = li%384; cattnT[li] = f2bf(c_attn_w[k*1152 + n]); continue; }
    li -= S_cattn;
    if (li < S_sq) { long n = li/384, k = li%384; cprojT[li] = f2bf(c_proj_w[k*384 + n]); continue; }
    li -= S_sq;
    if (li < S_sq) { long n = li/384, k = li%384; wkT[li] = f2bf(wk[k*384 + n]); continue; }
    li -= S_sq;
    if (li < S_sq) { long n = li/384, k = li%384; wvT[li] = f2bf(wv[k*384 + n]); continue; }
    li -= S_sq;
    if (li < S_fc) { long n = li/384, k = li%384; fcT[li] = f2bf(fc_w[k*1536 + n]); continue; }
    li -= S_fc;
    if (li < S_pr) { long n = li/1536, k = li%1536; prT[li] = f2bf(pr_w[k*384 + n]); continue; }
    li -= S_pr;
    if (li < S_w1) { long n = li/384, k = li%384; w1tr[li] = f2bf(mw1[k*768 + n]); continue; }
    li -= S_w1;
    if (li < S_w2) { long n = li/768, k = li%768; w2tr[li] = f2bf(mw2[k*384 + n]); continue; }
    li -= S_w2;
    if (li < S_w2p) { w2pl[li] = f2bf(mw2[li]); continue; }
    li -= S_w2p;
    if (li < S_mq) { memq[li] = f2bf(mem_q[li]); continue; }
    li -= S_mq;
    { long r = li/384, c = li%384;
      unsigned short v = f2bf(persist[li]);
      seqb[r*384 + c] = v;
      seqb[(148 + r)*384 + c] = v; }
  }
}

// ---------- LayerNorms ----------
__global__ __launch_bounds__(384)
void ln1_k(const float* __restrict__ x, const float* __restrict__ g, const float* __restrict__ b,
           unsigned short* __restrict__ seqb)
{
  int row = blockIdx.x, tid = threadIdx.x;
  float v = x[(long)row*Cc + tid];
  int lane = tid & 63, wid = tid >> 6;
  __shared__ float red[6];
  __shared__ float mu_s, rstd_s;
  float s = v;
  #pragma unroll
  for (int off = 32; off; off >>= 1) s += __shfl_down(s, off);
  if (lane == 0) red[wid] = s;
  __syncthreads();
  if (tid == 0) { float t = 0; for (int i = 0; i < 6; ++i) t += red[i]; mu_s = t/(float)Cc; }
  __syncthreads();
  float d = v - mu_s, sq = d*d;
  #pragma unroll
  for (int off = 32; off; off >>= 1) sq += __shfl_down(sq, off);
  if (lane == 0) red[wid] = sq;
  __syncthreads();
  if (tid == 0) { float t = 0; for (int i = 0; i < 6; ++i) t += red[i]; rstd_s = rsqrtf(t/(float)Cc + 1e-5f); }
  __syncthreads();
  int z = row >> 7, t = row & 127;
  seqb[((long)z*TT + PL_ + t)*Cc + tid] = f2bf(d*rstd_s*g[tid] + b[tid]);
}

__global__ __launch_bounds__(384)
void ln2_k(const float* __restrict__ x, const float* __restrict__ g, const float* __restrict__ b,
           unsigned short* __restrict__ out)
{
  int row = blockIdx.x, tid = threadIdx.x;
  float v = x[(long)row*Cc + tid];
  int lane = tid & 63, wid = tid >> 6;
  __shared__ float red[6];
  __shared__ float mu_s, rstd_s;
  float s = v;
  #pragma unroll
  for (int off = 32; off; off >>= 1) s += __shfl_down(s, off);
  if (lane == 0) red[wid] = s;
  __syncthreads();
  if (tid == 0) { float t = 0; for (int i = 0; i < 6; ++i) t += red[i]; mu_s = t/(float)Cc; }
  __syncthreads();
  float d = v - mu_s, sq = d*d;
  #pragma unroll
  for (int off = 32; off; off >>= 1) sq += __shfl_down(sq, off);
  if (lane == 0) red[wid] = sq;
  __syncthreads();
  if (tid == 0) { float t = 0; for (int i = 0; i < 6; ++i) t += red[i]; rstd_s = rsqrtf(t/(float)Cc + 1e-5f); }
  __syncthreads();
  out[(long)row*Cc + tid] = f2bf(d*rstd_s*g[tid] + b[tid]);
}

// ---------- attention (f32 math, bf16 out) ----------
__global__ __launch_bounds__(64)
void attn_k(const float* __restrict__ qkv, unsigned short* __restrict__ yb)
{
  const int Cq = 3*Cc;
  int lane = threadIdx.x;
  int qr = PL_ + blockIdx.x;
  int h  = blockIdx.y;
  int b  = blockIdx.z;
  const float* base = qkv + (long)(b*TT)*Cq;
  __shared__ float qs[HD];
  __shared__ float p[TT];
  qs[lane] = base[(long)qr*Cq + h*HD + lane];
  __syncthreads();
  float mloc = -1e30f;
  for (int k = lane; k < TT; k += 64) {
    float s = -1e30f;
    if (k <= qr) {
      const float* kp = base + (long)k*Cq + Cc + h*HD;
      float acc = 0.f;
      #pragma unroll
      for (int d2 = 0; d2 < HD; ++d2) acc += qs[d2]*kp[d2];
      s = acc * 0.125f;
    }
    p[k] = s;
    mloc = fmaxf(mloc, s);
  }
  #pragma unroll
  for (int off = 32; off; off >>= 1) mloc = fmaxf(mloc, __shfl_xor(mloc, off));
  float ssum = 0.f;
  for (int k = lane; k < TT; k += 64) {
    float e = (k <= qr) ? expf(p[k] - mloc) : 0.f;
    p[k] = e;
    ssum += e;
  }
  #pragma unroll
  for (int off = 32; off; off >>= 1) ssum += __shfl_xor(ssum, off);
  __syncthreads();
  float inv = 1.f / ssum;
  float acc = 0.f;
  for (int k = 0; k <= qr; ++k)
    acc += p[k] * base[(long)k*Cq + 2*Cc + h*HD + lane];
  yb[((long)(b*T_ + blockIdx.x))*Cc + h*HD + lane] = f2bf(acc * inv);
}

// ---------- launch ----------
extern "C" void kernel_launch(void* const* d_in, const int* in_sizes, int n_in,
                              void* d_out, int out_size, void* d_ws, size_t ws_size,
                              hipStream_t stream)
{
  const float* x        = (const float*)d_in[0];
  const float* c_attn_w = (const float*)d_in[1];
  const float* c_attn_b = (const float*)d_in[2];
  const float* c_proj_w = (const float*)d_in[3];
  const float* c_proj_b = (const float*)d_in[4];
  const float* ln1_g    = (const float*)d_in[5];
  const float* ln1_b    = (const float*)d_in[6];
  const float* ln2_g    = (const float*)d_in[7];
  const float* ln2_b    = (const float*)d_in[8];
  const float* fc_w     = (const float*)d_in[9];
  const float* fc_b     = (const float*)d_in[10];
  const float* pr_w     = (const float*)d_in[11];
  const float* pr_b     = (const float*)d_in[12];
  const float* mem_w1   = (const float*)d_in[13];
  const float* mem_w2   = (const float*)d_in[14];
  const float* wk       = (const float*)d_in[15];
  const float* wv       = (const float*)d_in[16];
  const float* mem_q    = (const float*)d_in[17];
  const float* persist  = (const float*)d_in[18];

  // f32 pool
  float* qkv = (float*)d_ws;                    // [296][1152]
  float* vmb = qkv + 296L*1152;                 // [256][384]
  float* h1  = vmb + 256L*384;                  // [256][384]
  float* h2  = h1  + 256L*384;                  // [256][384]
  float* hhb = h2  + 256L*384;                  // [256][768]
  // bf16 pool
  unsigned short* bp     = (unsigned short*)(hhb + 256L*768);
  unsigned short* cattnT = bp;                   bp += 1152L*384;
  unsigned short* cprojT = bp;                   bp += 384L*384;
  unsigned short* wkT    = bp;                   bp += 384L*384;
  unsigned short* wvT    = bp;                   bp += 384L*384;
  unsigned short* fcT    = bp;                   bp += 1536L*384;
  unsigned short* prT    = bp;                   bp += 384L*1536;
  unsigned short* w1tr   = bp;                   bp += 768L*384;
  unsigned short* w2tr   = bp;                   bp += 384L*768;
  unsigned short* w2pl   = bp;                   bp += 768L*384;
  unsigned short* memq   = bp;                   bp += 16L*384;
  unsigned short* seqb   = bp;                   bp += 2L*TT*384;
  unsigned short* hid    = bp;                   bp += 16L*768;
  unsigned short* yb     = bp;                   bp += 256L*384;
  unsigned short* h2n    = bp;                   bp += 256L*384;
  unsigned short* fco    = bp;                   bp += 256L*1536;
  unsigned short* h2b    = bp;                   bp += 256L*384;
  unsigned short* kmb    = bp;                   bp += 256L*384;
  unsigned short* kmTc   = bp;                   bp += 2L*384*128;
  unsigned short* ab     = bp;                   bp += 256L*768;
  unsigned short* abTc   = bp;                   bp += 2L*768*128;
  unsigned short* errB   = bp;                   bp += 256L*384;
  unsigned short* errT   = bp;                   bp += 2L*384*128;
  unsigned short* dhT    = bp;                   bp += 2L*768*128;
  unsigned short* w1fT   = bp;                   bp += 2L*768*384;
  unsigned short* w2fT   = bp;                   bp += 2L*384*768;
  unsigned short* ub     = bp;                   bp += 2L*128*768;
  float* outp = (float*)d_out;

  const float dpow  = powf(0.999f, 128.f);
  const float scale = -0.001f;

  // 1. convert weights (+persist rows into seq)
  convert_k<<<2048, 256, 0, stream>>>(c_attn_w, c_proj_w, wk, wv, fc_w, pr_w,
      mem_w1, mem_w2, mem_q, persist,
      cattnT, cprojT, wkT, wvT, fcT, prT, w1tr, w2tr, w2pl, memq, seqb);

  // 2. LN1 -> seq suffix rows (bf16)
  ln1_k<<<B_*T_, Cc, 0, stream>>>(x, ln1_g, ln1_b, seqb);

  // 3. hid = silu(memq @ mem_w1)    M=16,N=768,K=384
  gemm_k<12,2,false,false,false,true,false><<<dim3(6,1,1), 256, 0, stream>>>(
      memq, w1tr, nullptr, nullptr, 0.f, nullptr, hid, nullptr, 16, 768, 0,0,0,0);

  // 4. retr = hid @ mem_w2 -> seq rows 4..19 both batches   M=16,N=384,K=768
  mem2_k<<<dim3(3,1,1), 256, 0, stream>>>(hid, w2tr, seqb);

  // 5. fused qkv/km/vm   M=296,N=1920,K=384
  qkv_k<<<dim3(15,5,1), 256, 0, stream>>>(seqb, cattnT, wkT, wvT, c_attn_b,
                                          qkv, kmb, kmTc, vmb);

  // 6. attention
  attn_k<<<dim3(T_, NH_, B_), 64, 0, stream>>>(qkv, yb);

  // 7. h1 = x + yb @ c_proj + b    M=256,N=384,K=384
  gemm_k<12,0,true,true,true,false,false><<<dim3(3,4,1), 256, 0, stream>>>(
      yb, cprojT, c_proj_b, x, 1.f, h1, nullptr, nullptr, 256, 384, 0,0,0,0);

  // 8. ln2 -> h2n bf16
  ln2_k<<<B_*T_, Cc, 0, stream>>>(h1, ln2_g, ln2_b, h2n);

  // 9. fco = gelu(h2n @ fc + b)    M=256,N=1536,K=384
  gemm_k<12,1,true,false,false,true,false><<<dim3(12,4,1), 256, 0, stream>>>(
      h2n, fcT, fc_b, nullptr, 0.f, nullptr, fco, nullptr, 256, 1536, 0,0,0,0);

  // 10. h2 = h1 + fco @ pr + b  (f32 + bf16)   M=256,N=384,K=1536
  gemm_k<48,0,true,true,true,true,false><<<dim3(3,4,1), 256, 0, stream>>>(
      fco, prT, pr_b, h1, 1.f, h2, h2b, nullptr, 256, 384, 0,0,0,0);

  // 11. hh/ab/abTc    M=256,N=768,K=384
  hh_k<<<dim3(6,4,1), 256, 0, stream>>>(kmb, w1tr, hhb, ab, abTc);

  // 12. err = ab @ mem_w2 - vm  (bf16 + transposed)   M=256,N=384,K=768
  gemm_k<24,0,false,true,false,true,true><<<dim3(3,4,1), 256, 0, stream>>>(
      ab, w2tr, nullptr, vmb, -1.f, nullptr, errB, errT, 256, 384, 0,0,0,0);

  // 13. dhT = ((err @ W2^T) * dsilu(hh))^T   M=256,N=768,K=384
  dh_k<<<dim3(6,4,1), 256, 0, stream>>>(errB, w2pl, hhb, dhT);

  // 14. w1fT[z] : M=384,N=768,K=128  (A=kmTc, BT=dhT, W0=mem_w1)
  wupd_k<<<dim3(6,6,2), 256, 0, stream>>>(kmTc, dhT, mem_w1, w1fT, 384, 768, scale, dpow);

  // 15. w2fT[z] : M=768,N=384,K=128  (A=abTc, BT=errT, W0=mem_w2)
  wupd_k<<<dim3(3,12,2), 256, 0, stream>>>(abTc, errT, mem_w2, w2fT, 768, 384, scale, dpow);

  // 16. ub = silu(h2 @ w1f)   per-z  M=128,N=768,K=384
  gemm_k<12,2,false,false,false,true,false><<<dim3(6,2,2), 256, 0, stream>>>(
      h2b, w1fT, nullptr, nullptr, 0.f, nullptr, ub, nullptr, 128, 768,
      128L*384, 768L*384, 128L*768, 0);

  // 17. out = h2 + ub @ w2f   per-z  M=128,N=384,K=768
  gemm_k<24,0,false,true,true,false,false><<<dim3(3,2,2), 256, 0, stream>>>(
      ub, w2fT, nullptr, h2, 1.f, outp, nullptr, nullptr, 128, 384,
      128L*768, 384L*768, 128L*384, 128L*384);
}

// Round 4
// 121.122 us; speedup vs baseline: 4.2239x; 2.2252x over previous
//
#include <hip/hip_runtime.h>
#include <math.h>

#define B_ 2
#define T_ 128
#define Cc 384
#define NH_ 6
#define HD 64
#define Hh 768
#define P_ 4
#define M_ 16
#define PL_ 20
#define TT 148

typedef unsigned short u16;
typedef short short8 __attribute__((ext_vector_type(8)));
typedef float f32x4 __attribute__((ext_vector_type(4)));

static inline int cdiv(int a, int b) { return (a + b - 1) / b; }

// ---------- helpers ----------
__device__ __forceinline__ u16 f2bf(float f) {
  unsigned int u = __float_as_uint(f);
  u += 0x7FFFu + ((u >> 16) & 1u);
  return (u16)(u >> 16);
}
__device__ __forceinline__ float siluf(float v) { return v / (1.f + expf(-v)); }
__device__ __forceinline__ float geluf(float v) {
  float x3 = v*v*v;
  return 0.5f*v*(1.f + tanhf(0.7978845608028654f*(v + 0.044715f*x3)));
}
template<int ACT> __device__ __forceinline__ float act_apply(float v) {
  if (ACT == 1) return geluf(v);
  if (ACT == 2) return siluf(v);
  return v;
}
// coef[t] = (0.999^(128-t) - 0.9^(128-t)) / 0.099  via exp2
__device__ __forceinline__ float coef_f(int k) {
  float e = (float)(T_ - k);
  return (exp2f(e * -0.00144342f) - exp2f(e * -0.15200310f)) * (1.0f/0.099f);
}
__device__ __forceinline__ void st_tr4(u16* dst, float v0, float v1, float v2, float v3) {
  union { u16 u[4]; uint2 d; } q;
  q.u[0]=f2bf(v0); q.u[1]=f2bf(v1); q.u[2]=f2bf(v2); q.u[3]=f2bf(v3);
  *(uint2*)dst = q.d;
}

// ---------- MFMA core with wave-split-K ----------
// Block = 4 waves; all waves compute the SAME 32x64 tile, each over K/4.
// Partials land in red[w][col(64)][row(36 pad)]; caller reduces.
template<int KSTEPS>   // per-wave K-steps; total K = KSTEPS*128
__device__ __forceinline__ void mfma_core(const u16* __restrict__ A,
    const u16* __restrict__ BT, int M, int mBase, int nBase,
    float (*red)[64][36])
{
  const long K = (long)KSTEPS * 128;
  int l = threadIdx.x & 63, w = threadIdx.x >> 6;
  int lr = l & 15, kg = l >> 4;
  long r0 = (long)min(mBase + lr, M - 1);
  long r1 = (long)min(mBase + 16 + lr, M - 1);
  long c0 = nBase + lr;
  long ko = (long)w * KSTEPS * 32 + kg * 8;
  const u16* pa0 = A + r0*K + ko;
  const u16* pa1 = A + r1*K + ko;
  const u16* pb0 = BT + c0*K + ko;
  const u16* pb1 = BT + (c0+16)*K + ko;
  const u16* pb2 = BT + (c0+32)*K + ko;
  const u16* pb3 = BT + (c0+48)*K + ko;
  f32x4 acc[2][4] = {};
  short8 a0 = *(const short8*)pa0, a1 = *(const short8*)pa1;
  short8 b0 = *(const short8*)pb0, b1 = *(const short8*)pb1;
  short8 b2 = *(const short8*)pb2, b3 = *(const short8*)pb3;
  #pragma unroll
  for (int t = 0; t < KSTEPS; ++t) {
    short8 xa0=a0, xa1=a1, xb0=b0, xb1=b1, xb2=b2, xb3=b3;
    if (t+1 < KSTEPS) {
      int o = (t+1)*32;
      a0 = *(const short8*)(pa0+o); a1 = *(const short8*)(pa1+o);
      b0 = *(const short8*)(pb0+o); b1 = *(const short8*)(pb1+o);
      b2 = *(const short8*)(pb2+o); b3 = *(const short8*)(pb3+o);
    }
    acc[0][0] = __builtin_amdgcn_mfma_f32_16x16x32_bf16(xa0, xb0, acc[0][0], 0,0,0);
    acc[0][1] = __builtin_amdgcn_mfma_f32_16x16x32_bf16(xa0, xb1, acc[0][1], 0,0,0);
    acc[0][2] = __builtin_amdgcn_mfma_f32_16x16x32_bf16(xa0, xb2, acc[0][2], 0,0,0);
    acc[0][3] = __builtin_amdgcn_mfma_f32_16x16x32_bf16(xa0, xb3, acc[0][3], 0,0,0);
    acc[1][0] = __builtin_amdgcn_mfma_f32_16x16x32_bf16(xa1, xb0, acc[1][0], 0,0,0);
    acc[1][1] = __builtin_amdgcn_mfma_f32_16x16x32_bf16(xa1, xb1, acc[1][1], 0,0,0);
    acc[1][2] = __builtin_amdgcn_mfma_f32_16x16x32_bf16(xa1, xb2, acc[1][2], 0,0,0);
    acc[1][3] = __builtin_amdgcn_mfma_f32_16x16x32_bf16(xa1, xb3, acc[1][3], 0,0,0);
  }
  #pragma unroll
  for (int i = 0; i < 2; ++i)
    #pragma unroll
    for (int j = 0; j < 4; ++j)
      *(f32x4*)&red[w][j*16 + lr][i*16 + kg*4] = acc[i][j];
  __syncthreads();
}

// Each thread reduces 8 rows of one column: col=tid&63, rows rg*8..+7.
__device__ __forceinline__ void reduce8(float (*red)[64][36], float v[8], int& row0, int& col) {
  int tid = threadIdx.x;
  col = tid & 63;
  row0 = (tid >> 6) * 8;
  #pragma unroll
  for (int q = 0; q < 2; ++q) {
    f32x4 s = *(f32x4*)&red[0][col][row0 + q*4];
    s += *(f32x4*)&red[1][col][row0 + q*4];
    s += *(f32x4*)&red[2][col][row0 + q*4];
    s += *(f32x4*)&red[3][col][row0 + q*4];
    v[q*4+0] = s[0]; v[q*4+1] = s[1]; v[q*4+2] = s[2]; v[q*4+3] = s[3];
  }
}

// ---------- generic gemm ----------
template<int KSTEPS, int ACT, bool BIAS, bool RES, bool STF, bool STB, bool STTR>
__global__ __launch_bounds__(256)
void gemm_k(const u16* __restrict__ A, const u16* __restrict__ BT,
            const float* __restrict__ bias, const float* __restrict__ res, float rscale,
            float* __restrict__ outF, u16* __restrict__ outB, u16* __restrict__ outT,
            int M, int N, long sA, long sB, long sOut, long sR)
{
  __shared__ float red[4][64][36];
  int z = blockIdx.z;
  int mBase = blockIdx.y*32, nBase = blockIdx.x*64;
  mfma_core<KSTEPS>(A + (long)z*sA, BT + (long)z*sB, M, mBase, nBase, red);
  float v[8]; int row0, col;
  reduce8(red, v, row0, col);
  int c = nBase + col;
  float bv = BIAS ? bias[c] : 0.f;
  #pragma unroll
  for (int q = 0; q < 8; ++q) {
    int r = mBase + row0 + q;
    float val = act_apply<ACT>(v[q] + bv);
    if (RES && r < M) val += rscale * res[(long)z*sR + (long)r*N + c];
    v[q] = val;
    if (r < M) {
      if (STF) outF[(long)z*sOut + (long)r*N + c] = val;
      if (STB) outB[(long)z*sOut + (long)r*N + c] = f2bf(val);
    }
  }
  if (STTR) {
    #pragma unroll
    for (int q = 0; q < 2; ++q) {
      int r = mBase + row0 + q*4;
      if (r < M) {
        int zz = r >> 7, t0 = r & 127;
        st_tr4(&outT[((long)zz*N + c)*128 + t0], v[q*4], v[q*4+1], v[q*4+2], v[q*4+3]);
      }
    }
  }
}

// ---------- fused qkv/km/vm ----------
__global__ __launch_bounds__(256)
void qkv_k(const u16* __restrict__ seqb, const u16* __restrict__ cattnT,
           const u16* __restrict__ wkT, const u16* __restrict__ wvT,
           const float* __restrict__ cab, float* __restrict__ qkv,
           u16* __restrict__ km, u16* __restrict__ kmTc, float* __restrict__ vm)
{
  __shared__ float red[4][64][36];
  int nb = blockIdx.x * 64;
  const u16* BT; int n0, seg;
  if (nb < 1152)      { BT = cattnT; n0 = nb;        seg = 0; }
  else if (nb < 1536) { BT = wkT;    n0 = nb - 1152; seg = 1; }
  else                { BT = wvT;    n0 = nb - 1536; seg = 2; }
  int mBase = blockIdx.y*32;
  mfma_core<3>(seqb, BT, 296, mBase, n0, red);
  float v[8]; int row0, col;
  reduce8(red, v, row0, col);
  int c = n0 + col;
  if (seg == 0) {
    float bv = cab[c];
    #pragma unroll
    for (int q = 0; q < 8; ++q) {
      int r = mBase + row0 + q;
      if (r < 296) qkv[(long)r*1152 + c] = v[q] + bv;
    }
  } else if (seg == 1) {
    #pragma unroll
    for (int q = 0; q < 8; ++q) {
      int r = mBase + row0 + q;
      if (r < 296) {
        int z = r/148, t = r - 20 - z*148;
        if (t >= 0) km[((long)z*128 + t)*384 + c] = f2bf(v[q]);
      }
    }
    #pragma unroll
    for (int q = 0; q < 2; ++q) {
      int r = mBase + row0 + q*4;
      if (r < 296) {
        int z = r/148, t0 = r - 20 - z*148;
        if (t0 >= 0)
          st_tr4(&kmTc[((long)z*384 + c)*128 + t0],
                 v[q*4]*coef_f(t0), v[q*4+1]*coef_f(t0+1),
                 v[q*4+2]*coef_f(t0+2), v[q*4+3]*coef_f(t0+3));
      }
    }
  } else {
    #pragma unroll
    for (int q = 0; q < 8; ++q) {
      int r = mBase + row0 + q;
      if (r < 296) {
        int z = r/148, t = r - 20 - z*148;
        if (t >= 0) vm[((long)z*128 + t)*384 + c] = v[q];
      }
    }
  }
}

// ---------- hh = km@w1: hh f32, ab=silu bf16, abTc=silu*coef transposed ----------
__global__ __launch_bounds__(256)
void hh_k(const u16* __restrict__ km, const u16* __restrict__ w1tr,
          float* __restrict__ hh, u16* __restrict__ ab, u16* __restrict__ abTc)
{
  __shared__ float red[4][64][36];
  int mBase = blockIdx.y*32, nBase = blockIdx.x*64;
  mfma_core<3>(km, w1tr, 256, mBase, nBase, red);
  float v[8]; int row0, col;
  reduce8(red, v, row0, col);
  int c = nBase + col;
  float s8[8];
  #pragma unroll
  for (int q = 0; q < 8; ++q) {
    int r = mBase + row0 + q;
    hh[(long)r*768 + c] = v[q];
    s8[q] = siluf(v[q]);
    ab[(long)r*768 + c] = f2bf(s8[q]);
  }
  #pragma unroll
  for (int q = 0; q < 2; ++q) {
    int r = mBase + row0 + q*4;
    int zz = r >> 7, t0 = r & 127;
    st_tr4(&abTc[((long)zz*768 + c)*128 + t0],
           s8[q*4]*coef_f(t0), s8[q*4+1]*coef_f(t0+1),
           s8[q*4+2]*coef_f(t0+2), s8[q*4+3]*coef_f(t0+3));
  }
}

// ---------- dhT = ((err @ W2^T) * dsilu(hh))^T ----------
__global__ __launch_bounds__(256)
void dh_k(const u16* __restrict__ errB, const u16* __restrict__ w2pl,
          const float* __restrict__ hh, u16* __restrict__ dhT)
{
  __shared__ float red[4][64][36];
  int mBase = blockIdx.y*32, nBase = blockIdx.x*64;
  mfma_core<3>(errB, w2pl, 256, mBase, nBase, red);
  float v[8]; int row0, col;
  reduce8(red, v, row0, col);
  int c = nBase + col;
  #pragma unroll
  for (int q = 0; q < 8; ++q) {
    int r = mBase + row0 + q;
    float h = hh[(long)r*768 + c];
    float sg = 1.f/(1.f + expf(-h));
    v[q] = v[q] * (sg*(1.f + h*(1.f - sg)));
  }
  #pragma unroll
  for (int q = 0; q < 2; ++q) {
    int r = mBase + row0 + q*4;
    int zz = r >> 7, t0 = r & 127;
    st_tr4(&dhT[((long)zz*768 + c)*128 + t0], v[q*4], v[q*4+1], v[q*4+2], v[q*4+3]);
  }
}

// ---------- weight update: outT[z][n][m] = dpow*W0[m][n] + scale*acc ----------
__global__ __launch_bounds__(256)
void wupd_k(const u16* __restrict__ A, const u16* __restrict__ BT,
            const float* __restrict__ W0, u16* __restrict__ outT,
            int M, int N, float scale, float dpow)
{
  __shared__ float red[4][64][36];
  int z = blockIdx.z;
  const u16* Az = A + (long)z*M*128;
  const u16* Bz = BT + (long)z*N*128;
  u16* Oz = outT + (long)z*M*N;
  int mBase = blockIdx.y*32, nBase = blockIdx.x*64;
  mfma_core<1>(Az, Bz, M, mBase, nBase, red);
  float v[8]; int row0, col;
  reduce8(red, v, row0, col);
  int c = nBase + col;
  #pragma unroll
  for (int q = 0; q < 8; ++q) {
    int r = mBase + row0 + q;
    v[q] = dpow*W0[(long)r*N + c] + scale*v[q];
  }
  int r0 = mBase + row0;
  st_tr4(&Oz[(long)c*M + r0],     v[0], v[1], v[2], v[3]);
  st_tr4(&Oz[(long)c*M + r0 + 4], v[4], v[5], v[6], v[7]);
}

// ---------- retr -> seq rows 4..19 (both batches) ----------
__global__ __launch_bounds__(256)
void mem2_k(const u16* __restrict__ hid, const u16* __restrict__ w2tr,
            u16* __restrict__ seqb)
{
  __shared__ float red[4][64][36];
  int nBase = blockIdx.x*64;
  mfma_core<6>(hid, w2tr, 16, 0, nBase, red);
  float v[8]; int row0, col;
  reduce8(red, v, row0, col);
  int c = nBase + col;
  #pragma unroll
  for (int q = 0; q < 8; ++q) {
    int r = row0 + q;
    if (r < 16) {
      u16 b = f2bf(v[q]);
      seqb[(long)(P_ + r)*384 + c] = b;
      seqb[(long)(TT + P_ + r)*384 + c] = b;
    }
  }
}

// ---------- coalesced transpose+convert: f32 [K][N] -> bf16 [N][K] ----------
__global__ __launch_bounds__(256)
void transp_k(const float* __restrict__ s0, const float* __restrict__ s1,
              const float* __restrict__ s2, const float* __restrict__ s3,
              const float* __restrict__ s4, const float* __restrict__ s5,
              const float* __restrict__ s6, const float* __restrict__ s7,
              u16* __restrict__ d0, u16* __restrict__ d1, u16* __restrict__ d2,
              u16* __restrict__ d3, u16* __restrict__ d4, u16* __restrict__ d5,
              u16* __restrict__ d6, u16* __restrict__ d7)
{
  int b = blockIdx.x;
  const float* src; u16* dst; int K, N, tile;
  if (b < 432)       { src=s0; dst=d0; K=384;  N=1152; tile=b; }
  else if (b < 576)  { src=s1; dst=d1; K=384;  N=384;  tile=b-432; }
  else if (b < 720)  { src=s2; dst=d2; K=384;  N=384;  tile=b-576; }
  else if (b < 864)  { src=s3; dst=d3; K=384;  N=384;  tile=b-720; }
  else if (b < 1440) { src=s4; dst=d4; K=384;  N=1536; tile=b-864; }
  else if (b < 2016) { src=s5; dst=d5; K=1536; N=384;  tile=b-1440; }
  else if (b < 2304) { src=s6; dst=d6; K=384;  N=768;  tile=b-2016; }
  else               { src=s7; dst=d7; K=768;  N=384;  tile=b-2304; }
  int ntx = N >> 5;
  int n0 = (tile % ntx) << 5, k0 = (tile / ntx) << 5;
  __shared__ float fl[32][33];
  int tr = threadIdx.x >> 3, tc4 = (threadIdx.x & 7) << 2;
  float4 vv = *(const float4*)&src[(long)(k0 + tr)*N + n0 + tc4];
  fl[tr][tc4] = vv.x; fl[tr][tc4+1] = vv.y; fl[tr][tc4+2] = vv.z; fl[tr][tc4+3] = vv.w;
  __syncthreads();
  st_tr4(&dst[(long)(n0 + tr)*K + k0 + tc4],
         fl[tc4][tr], fl[tc4+1][tr], fl[tc4+2][tr], fl[tc4+3][tr]);
}

// ---------- plain converts: w2pl, memq, persist->seqb(dup) ----------
__global__ __launch_bounds__(256)
void plain_k(const float* __restrict__ mw2, const float* __restrict__ mem_q,
             const float* __restrict__ persist, u16* __restrict__ w2pl,
             u16* __restrict__ memq, u16* __restrict__ seqb)
{
  const int n_w2 = (768*384)/4, n_mq = (16*384)/4, n_ps = (4*384)/4;
  int i = blockIdx.x*blockDim.x + threadIdx.x;
  if (i < n_w2) {
    float4 v = *(const float4*)&mw2[i*4];
    st_tr4(&w2pl[i*4], v.x, v.y, v.z, v.w);
  } else if (i < n_w2 + n_mq) {
    int j = i - n_w2;
    float4 v = *(const float4*)&mem_q[j*4];
    st_tr4(&memq[j*4], v.x, v.y, v.z, v.w);
  } else if (i < n_w2 + n_mq + n_ps) {
    int j = i - n_w2 - n_mq;
    float4 v = *(const float4*)&persist[j*4];
    st_tr4(&seqb[j*4], v.x, v.y, v.z, v.w);
    st_tr4(&seqb[148*384 + j*4], v.x, v.y, v.z, v.w);
  }
}

// ---------- LayerNorms ----------
__global__ __launch_bounds__(384)
void ln1_k(const float* __restrict__ x, const float* __restrict__ g, const float* __restrict__ b,
           u16* __restrict__ seqb)
{
  int row = blockIdx.x, tid = threadIdx.x;
  float v = x[(long)row*Cc + tid];
  int lane = tid & 63, wid = tid >> 6;
  __shared__ float red[6];
  __shared__ float mu_s, rstd_s;
  float s = v;
  #pragma unroll
  for (int off = 32; off; off >>= 1) s += __shfl_down(s, off);
  if (lane == 0) red[wid] = s;
  __syncthreads();
  if (tid == 0) { float t = 0; for (int i = 0; i < 6; ++i) t += red[i]; mu_s = t/(float)Cc; }
  __syncthreads();
  float d = v - mu_s, sq = d*d;
  #pragma unroll
  for (int off = 32; off; off >>= 1) sq += __shfl_down(sq, off);
  if (lane == 0) red[wid] = sq;
  __syncthreads();
  if (tid == 0) { float t = 0; for (int i = 0; i < 6; ++i) t += red[i]; rstd_s = rsqrtf(t/(float)Cc + 1e-5f); }
  __syncthreads();
  int z = row >> 7, t = row & 127;
  seqb[((long)z*TT + PL_ + t)*Cc + tid] = f2bf(d*rstd_s*g[tid] + b[tid]);
}

__global__ __launch_bounds__(384)
void ln2_k(const float* __restrict__ x, const float* __restrict__ g, const float* __restrict__ b,
           u16* __restrict__ out)
{
  int row = blockIdx.x, tid = threadIdx.x;
  float v = x[(long)row*Cc + tid];
  int lane = tid & 63, wid = tid >> 6;
  __shared__ float red[6];
  __shared__ float mu_s, rstd_s;
  float s = v;
  #pragma unroll
  for (int off = 32; off; off >>= 1) s += __shfl_down(s, off);
  if (lane == 0) red[wid] = s;
  __syncthreads();
  if (tid == 0) { float t = 0; for (int i = 0; i < 6; ++i) t += red[i]; mu_s = t/(float)Cc; }
  __syncthreads();
  float d = v - mu_s, sq = d*d;
  #pragma unroll
  for (int off = 32; off; off >>= 1) sq += __shfl_down(sq, off);
  if (lane == 0) red[wid] = sq;
  __syncthreads();
  if (tid == 0) { float t = 0; for (int i = 0; i < 6; ++i) t += red[i]; rstd_s = rsqrtf(t/(float)Cc + 1e-5f); }
  __syncthreads();
  out[(long)row*Cc + tid] = f2bf(d*rstd_s*g[tid] + b[tid]);
}

// ---------- attention ----------
__global__ __launch_bounds__(64)
void attn_k(const float* __restrict__ qkv, u16* __restrict__ yb)
{
  const int Cq = 3*Cc;
  int lane = threadIdx.x;
  int qr = PL_ + blockIdx.x;
  int h  = blockIdx.y;
  int b  = blockIdx.z;
  const float* base = qkv + (long)(b*TT)*Cq;
  __shared__ float qs[HD];
  __shared__ float p[TT];
  qs[lane] = base[(long)qr*Cq + h*HD + lane];
  __syncthreads();
  float mloc = -1e30f;
  for (int k = lane; k < TT; k += 64) {
    float s = -1e30f;
    if (k <= qr) {
      const float* kp = base + (long)k*Cq + Cc + h*HD;
      float acc = 0.f;
      #pragma unroll
      for (int d2 = 0; d2 < HD; ++d2) acc += qs[d2]*kp[d2];
      s = acc * 0.125f;
    }
    p[k] = s;
    mloc = fmaxf(mloc, s);
  }
  #pragma unroll
  for (int off = 32; off; off >>= 1) mloc = fmaxf(mloc, __shfl_xor(mloc, off));
  float ssum = 0.f;
  for (int k = lane; k < TT; k += 64) {
    float e = (k <= qr) ? expf(p[k] - mloc) : 0.f;
    p[k] = e;
    ssum += e;
  }
  #pragma unroll
  for (int off = 32; off; off >>= 1) ssum += __shfl_xor(ssum, off);
  __syncthreads();
  float inv = 1.f / ssum;
  float acc = 0.f;
  for (int k = 0; k <= qr; ++k)
    acc += p[k] * base[(long)k*Cq + 2*Cc + h*HD + lane];
  yb[((long)(b*T_ + blockIdx.x))*Cc + h*HD + lane] = f2bf(acc * inv);
}

// ---------- launch ----------
extern "C" void kernel_launch(void* const* d_in, const int* in_sizes, int n_in,
                              void* d_out, int out_size, void* d_ws, size_t ws_size,
                              hipStream_t stream)
{
  const float* x        = (const float*)d_in[0];
  const float* c_attn_w = (const float*)d_in[1];
  const float* c_attn_b = (const float*)d_in[2];
  const float* c_proj_w = (const float*)d_in[3];
  const float* c_proj_b = (const float*)d_in[4];
  const float* ln1_g    = (const float*)d_in[5];
  const float* ln1_b    = (const float*)d_in[6];
  const float* ln2_g    = (const float*)d_in[7];
  const float* ln2_b    = (const float*)d_in[8];
  const float* fc_w     = (const float*)d_in[9];
  const float* fc_b     = (const float*)d_in[10];
  const float* pr_w     = (const float*)d_in[11];
  const float* pr_b     = (const float*)d_in[12];
  const float* mem_w1   = (const float*)d_in[13];
  const float* mem_w2   = (const float*)d_in[14];
  const float* wk       = (const float*)d_in[15];
  const float* wv       = (const float*)d_in[16];
  const float* mem_q    = (const float*)d_in[17];
  const float* persist  = (const float*)d_in[18];

  // f32 pool
  float* qkv = (float*)d_ws;                    // [296][1152]
  float* vmb = qkv + 296L*1152;                 // [256][384]
  float* h1  = vmb + 256L*384;
  float* h2  = h1  + 256L*384;
  float* hhb = h2  + 256L*384;                  // [256][768]
  // bf16 pool
  u16* bp     = (u16*)(hhb + 256L*768);
  u16* cattnT = bp;  bp += 1152L*384;
  u16* cprojT = bp;  bp += 384L*384;
  u16* wkT    = bp;  bp += 384L*384;
  u16* wvT    = bp;  bp += 384L*384;
  u16* fcT    = bp;  bp += 1536L*384;
  u16* prT    = bp;  bp += 384L*1536;
  u16* w1tr   = bp;  bp += 768L*384;
  u16* w2tr   = bp;  bp += 384L*768;
  u16* w2pl   = bp;  bp += 768L*384;
  u16* memq   = bp;  bp += 16L*384;
  u16* seqb   = bp;  bp += 2L*TT*384;
  u16* hid    = bp;  bp += 16L*768;
  u16* yb     = bp;  bp += 256L*384;
  u16* h2n    = bp;  bp += 256L*384;
  u16* fco    = bp;  bp += 256L*1536;
  u16* h2b    = bp;  bp += 256L*384;
  u16* kmb    = bp;  bp += 256L*384;
  u16* kmTc   = bp;  bp += 2L*384*128;
  u16* ab     = bp;  bp += 256L*768;
  u16* abTc   = bp;  bp += 2L*768*128;
  u16* errB   = bp;  bp += 256L*384;
  u16* errT   = bp;  bp += 2L*384*128;
  u16* dhT    = bp;  bp += 2L*768*128;
  u16* w1fT   = bp;  bp += 2L*768*384;
  u16* w2fT   = bp;  bp += 2L*384*768;
  u16* ub     = bp;  bp += 2L*128*768;
  float* outp = (float*)d_out;

  const float dpow  = powf(0.999f, 128.f);
  const float scale = -0.001f;

  // 1-2. weight converts (coalesced transpose) + plain converts
  transp_k<<<2592, 256, 0, stream>>>(c_attn_w, c_proj_w, wk, wv, fc_w, pr_w, mem_w1, mem_w2,
                                     cattnT, cprojT, wkT, wvT, fcT, prT, w1tr, w2tr);
  plain_k<<<296, 256, 0, stream>>>(mem_w2, mem_q, persist, w2pl, memq, seqb);

  // 3. LN1 -> seq suffix
  ln1_k<<<B_*T_, Cc, 0, stream>>>(x, ln1_g, ln1_b, seqb);

  // 4. hid = silu(memq @ mem_w1)    M=16,N=768,K=384
  gemm_k<3,2,false,false,false,true,false><<<dim3(12,1,1), 256, 0, stream>>>(
      memq, w1tr, nullptr, nullptr, 0.f, nullptr, hid, nullptr, 16, 768, 0,0,0,0);

  // 5. retr -> seq rows 4..19   M=16,N=384,K=768
  mem2_k<<<dim3(6,1,1), 256, 0, stream>>>(hid, w2tr, seqb);

  // 6. fused qkv/km/vm   M=296,N=1920,K=384
  qkv_k<<<dim3(30,10,1), 256, 0, stream>>>(seqb, cattnT, wkT, wvT, c_attn_b,
                                           qkv, kmb, kmTc, vmb);

  // 7. attention
  attn_k<<<dim3(T_, NH_, B_), 64, 0, stream>>>(qkv, yb);

  // 8. h1 = x + yb @ c_proj + b   M=256,N=384,K=384
  gemm_k<3,0,true,true,true,false,false><<<dim3(6,8,1), 256, 0, stream>>>(
      yb, cprojT, c_proj_b, x, 1.f, h1, nullptr, nullptr, 256, 384, 0,0,0,0);

  // 9. ln2
  ln2_k<<<B_*T_, Cc, 0, stream>>>(h1, ln2_g, ln2_b, h2n);

  // 10. fco = gelu(h2n @ fc + b)   M=256,N=1536,K=384
  gemm_k<3,1,true,false,false,true,false><<<dim3(24,8,1), 256, 0, stream>>>(
      h2n, fcT, fc_b, nullptr, 0.f, nullptr, fco, nullptr, 256, 1536, 0,0,0,0);

  // 11. h2 = h1 + fco @ pr + b   M=256,N=384,K=1536
  gemm_k<12,0,true,true,true,true,false><<<dim3(6,8,1), 256, 0, stream>>>(
      fco, prT, pr_b, h1, 1.f, h2, h2b, nullptr, 256, 384, 0,0,0,0);

  // 12. hh/ab/abTc   M=256,N=768,K=384
  hh_k<<<dim3(12,8,1), 256, 0, stream>>>(kmb, w1tr, hhb, ab, abTc);

  // 13. err = ab @ mem_w2 - vm   M=256,N=384,K=768
  gemm_k<6,0,false,true,false,true,true><<<dim3(6,8,1), 256, 0, stream>>>(
      ab, w2tr, nullptr, vmb, -1.f, nullptr, errB, errT, 256, 384, 0,0,0,0);

  // 14. dhT   M=256,N=768,K=384
  dh_k<<<dim3(12,8,1), 256, 0, stream>>>(errB, w2pl, hhb, dhT);

  // 15. w1fT[z]  M=384,N=768,K=128
  wupd_k<<<dim3(12,12,2), 256, 0, stream>>>(kmTc, dhT, mem_w1, w1fT, 384, 768, scale, dpow);

  // 16. w2fT[z]  M=768,N=384,K=128
  wupd_k<<<dim3(6,24,2), 256, 0, stream>>>(abTc, errT, mem_w2, w2fT, 768, 384, scale, dpow);

  // 17. ub = silu(h2 @ w1f)   per-z M=128,N=768,K=384
  gemm_k<3,2,false,false,false,true,false><<<dim3(12,4,2), 256, 0, stream>>>(
      h2b, w1fT, nullptr, nullptr, 0.f, nullptr, ub, nullptr, 128, 768,
      128L*384, 768L*384, 128L*768, 0);

  // 18. out = h2 + ub @ w2f   per-z M=128,N=384,K=768
  gemm_k<6,0,false,true,true,false,false><<<dim3(6,4,2), 256, 0, stream>>>(
      ub, w2fT, nullptr, h2, 1.f, outp, nullptr, nullptr, 128, 384,
      128L*768, 384L*768, 128L*384, 128L*384);
}